// Round 13
// baseline (1516.286 us; speedup 1.0000x reference)
//
#include <hip/hip_runtime.h>

#define T_STEPS 2048
#define TOTAL   2080   // T_STEPS + 32 (deepest lag)

typedef float f2 __attribute__((ext_vector_type(2)));
typedef _Float16 h2 __attribute__((ext_vector_type(2)));

__device__ __forceinline__ float fast_rcp(float x) { return __builtin_amdgcn_rcpf(x); }

__device__ __forceinline__ float sig_f(float x) {
    return fast_rcp(1.0f + __expf(-x));
}
__device__ __forceinline__ float tanh_f(float x) {
    float e = __expf(-2.0f * x);
    return fmaf(2.0f, fast_rcp(1.0f + e), -1.0f);
}
__device__ __forceinline__ float gate_act(float x, float zm, float sm, float sa) {
    float e = __expf(-x * zm);
    return fmaf(fast_rcp(1.0f + e), sm, sa);
}

// f16 dot2 with f32 accumulate
#if __has_builtin(__builtin_amdgcn_fdot2)
#define FDOT2(a, b, c) __builtin_amdgcn_fdot2((a), (b), (c), false)
#else
__device__ __forceinline__ float FDOT2(h2 a, h2 b, float c) {
    return fmaf((float)a.x, (float)b.x, fmaf((float)a.y, (float)b.y, c));
}
#endif

// Drain ONLY lgkmcnt (LDS) before barrier — never vmcnt (R7 win).
#define LDS_BARRIER() asm volatile("s_waitcnt lgkmcnt(0)\n\ts_barrier" ::: "memory")

#define DPP_BCAST0 0x00
#define DPP_BCAST1 0x55
#define DPP_BCAST2 0xAA
#define DPP_BCAST3 0xFF
#define DPP_PAIR   0xF5    // quad_perm [1,1,3,3]: even lane gets odd partner's value
#define DPP_ROR4   0x124
#define DPP_ROR8   0x128
template<int CTRL>
__device__ __forceinline__ float dppf(float x) {
    int r = __builtin_amdgcn_update_dpp(0, __builtin_bit_cast(int, x), CTRL, 0xF, 0xF, true);
    return __builtin_bit_cast(float, r);
}

__device__ __forceinline__ void loadx4(float (&dst)[4], const float* __restrict__ x_r,
                                       const float* __restrict__ x_t,
                                       size_t xrb, size_t xtb, int l) {
#pragma unroll
    for (int u = 0; u < 4; ++u) {
        int v = l + 16 * u;
        dst[u] = (v < 47) ? x_r[xrb + v] : ((v < 49) ? x_t[xtb + (v - 47)] : 0.0f);
    }
}

__device__ __forceinline__ void unpack12(f2 (&in)[24], const float4* __restrict__ r4) {
#pragma unroll
    for (int u = 0; u < 12; ++u) {
        float4 v = r4[u];
        in[2 * u]     = f2{v.x, v.y};
        in[2 * u + 1] = f2{v.z, v.w};
    }
}

// 48 f16 (24 h2) as 6 ds_read_b128
__device__ __forceinline__ void unpackh(h2 (&in)[24], const h2* __restrict__ row) {
    const float4* q = (const float4*)row;
#pragma unroll
    for (int k = 0; k < 6; ++k) {
        float4 v = q[k];
        in[4 * k + 0] = __builtin_bit_cast(h2, v.x);
        in[4 * k + 1] = __builtin_bit_cast(h2, v.y);
        in[4 * k + 2] = __builtin_bit_cast(h2, v.z);
        in[4 * k + 3] = __builtin_bit_cast(h2, v.w);
    }
}

// Reassociated: 4 independent sub-chains (depth 6) per gate -> ~64cy latency
// instead of one 24-deep chain (~192cy). The recurrent waves' step time is
// dependent-chain-bound, so chain depth is the lever.
__device__ __forceinline__ float4 dot4h_r(const h2 (&in)[24], const h2 (&w)[4][24], float4 init) {
    float a00 = init.x, a01 = 0.f, a02 = 0.f, a03 = 0.f;
    float a10 = init.y, a11 = 0.f, a12 = 0.f, a13 = 0.f;
    float a20 = init.z, a21 = 0.f, a22 = 0.f, a23 = 0.f;
    float a30 = init.w, a31 = 0.f, a32 = 0.f, a33 = 0.f;
#pragma unroll
    for (int k = 0; k < 6; ++k) {
        a00 = FDOT2(w[0][k],      in[k],      a00);
        a01 = FDOT2(w[0][6 + k],  in[6 + k],  a01);
        a02 = FDOT2(w[0][12 + k], in[12 + k], a02);
        a03 = FDOT2(w[0][18 + k], in[18 + k], a03);
        a10 = FDOT2(w[1][k],      in[k],      a10);
        a11 = FDOT2(w[1][6 + k],  in[6 + k],  a11);
        a12 = FDOT2(w[1][12 + k], in[12 + k], a12);
        a13 = FDOT2(w[1][18 + k], in[18 + k], a13);
        a20 = FDOT2(w[2][k],      in[k],      a20);
        a21 = FDOT2(w[2][6 + k],  in[6 + k],  a21);
        a22 = FDOT2(w[2][12 + k], in[12 + k], a22);
        a23 = FDOT2(w[2][18 + k], in[18 + k], a23);
        a30 = FDOT2(w[3][k],      in[k],      a30);
        a31 = FDOT2(w[3][6 + k],  in[6 + k],  a31);
        a32 = FDOT2(w[3][12 + k], in[12 + k], a32);
        a33 = FDOT2(w[3][18 + k], in[18 + k], a33);
    }
    return float4{(a00 + a01) + (a02 + a03), (a10 + a11) + (a12 + a13),
                  (a20 + a21) + (a22 + a23), (a30 + a31) + (a32 + a33)};
}

// load a 47-col f32 weight row as 24 packed-f16 pairs (pad last to 0)
__device__ __forceinline__ void loadw47h(h2 (&w)[24], const float* __restrict__ src) {
#pragma unroll
    for (int u = 0; u < 23; ++u)
        w[u] = h2{(_Float16)src[2 * u], (_Float16)src[2 * u + 1]};
    w[23] = h2{(_Float16)src[46], (_Float16)0.0f};
}

__global__ __launch_bounds__(320) void adrnn_fused(
    const float* __restrict__ x_r, const float* __restrict__ x_t,
    const float* __restrict__ rWih0, const float* __restrict__ rWhh0,
    const float* __restrict__ rbih0, const float* __restrict__ rbhh0,
    const float* __restrict__ rWih1, const float* __restrict__ rWhh1,
    const float* __restrict__ rbih1, const float* __restrict__ rbhh1,
    const float* __restrict__ tWih0, const float* __restrict__ tWhh0,
    const float* __restrict__ tbih0, const float* __restrict__ tbhh0,
    const float* __restrict__ tWih1, const float* __restrict__ tWhh1,
    const float* __restrict__ tbih1, const float* __restrict__ tbhh1,
    float* __restrict__ r_out, float* __restrict__ t_out)
{
    __shared__ __align__(16) float tring[64][112]; // [x 0..48 | pad | h1 64..110 | pad]
    __shared__ __align__(16) h2 h0f16[16][32];     // h0(s), 24 h2 used
    __shared__ __align__(16) h2 h1f16[16][32];     // h1(s) for HB recurrence
    __shared__ __align__(16) float pAring[16][192];
    __shared__ __align__(16) float pBring[16][192];

    const int tid = threadIdx.x;
    const int wid = tid >> 6;
    const int l   = tid & 63;
    const int j   = l;
    const int b = blockIdx.x;
    const size_t xr_base = (size_t)b * T_STEPS * 47;
    const size_t xt_base = (size_t)b * T_STEPS * 2;

    if (tid < 256) {
        for (int k = tid; k < 64 * 48; k += 256) tring[k / 48][64 + (k % 48)] = 0.0f;
        for (int k = tid; k < 16 * 32; k += 256) {
            h0f16[k >> 5][k & 31] = h2{(_Float16)0.0f, (_Float16)0.0f};
            h1f16[k >> 5][k & 31] = h2{(_Float16)0.0f, (_Float16)0.0f};
        }
    }

    if (wid == 0) {
        // ===== XA (lag 0): pA(i) = Wih0*x(i)+b0, f32 path =====
        f2 w[4][24]; float w48[4]; float4 bias = {0, 0, 0, 0};
#pragma unroll
        for (int g = 0; g < 4; ++g) { w48[g] = 0.f;
#pragma unroll
            for (int u = 0; u < 24; ++u) w[g][u] = f2{0.f, 0.f}; }
        if (j < 47) {
            float bb[4];
#pragma unroll
            for (int g = 0; g < 4; ++g) {
                const int row = g * 47 + j;
#pragma unroll
                for (int u = 0; u < 24; ++u)
                    w[g][u] = f2{rWih0[row * 49 + 2 * u], rWih0[row * 49 + 2 * u + 1]};
                w48[g] = rWih0[row * 49 + 48];
                bb[g] = rbih0[row] + rbhh0[row];
            }
            bias = {bb[0], bb[1], bb[2], bb[3]};
        }
        __syncthreads();
        for (int i = 0; i < TOTAL; ++i) {
            if (i < T_STEPS && j < 47) {
                f2 in[24];
                unpack12(in, (const float4*)&tring[i & 63][0]);
                float x48 = tring[i & 63][48];
                // 2 sub-chains per gate (depth 12)
                f2 a0 = f2{bias.x, 0.f}, b0v = {0, 0};
                f2 a1 = f2{bias.y, 0.f}, b1v = {0, 0};
                f2 a2 = f2{bias.z, 0.f}, b2v = {0, 0};
                f2 a3 = f2{bias.w, 0.f}, b3v = {0, 0};
#pragma unroll
                for (int u = 0; u < 12; ++u) {
                    a0  = __builtin_elementwise_fma(w[0][u],      in[u],      a0);
                    b0v = __builtin_elementwise_fma(w[0][12 + u], in[12 + u], b0v);
                    a1  = __builtin_elementwise_fma(w[1][u],      in[u],      a1);
                    b1v = __builtin_elementwise_fma(w[1][12 + u], in[12 + u], b1v);
                    a2  = __builtin_elementwise_fma(w[2][u],      in[u],      a2);
                    b2v = __builtin_elementwise_fma(w[2][12 + u], in[12 + u], b2v);
                    a3  = __builtin_elementwise_fma(w[3][u],      in[u],      a3);
                    b3v = __builtin_elementwise_fma(w[3][12 + u], in[12 + u], b3v);
                }
                f2 s0 = a0 + b0v, s1 = a1 + b1v, s2 = a2 + b2v, s3 = a3 + b3v;
                float4 out;
                out.x = fmaf(w48[0], x48, s0.x + s0.y);
                out.y = fmaf(w48[1], x48, s1.x + s1.y);
                out.z = fmaf(w48[2], x48, s2.x + s2.y);
                out.w = fmaf(w48[3], x48, s3.x + s3.y);
                *(float4*)&pAring[i & 15][j * 4] = out;
            }
            if ((i & 7) == 7) LDS_BARRIER();
        }
    } else if (wid == 1) {
        // ===== HA (lag 8): h0(s) = cell(pA(s) + Whh0*h0(s-1)), f16 dots =====
        h2 w[4][24];
#pragma unroll
        for (int g = 0; g < 4; ++g)
#pragma unroll
            for (int u = 0; u < 24; ++u) w[g][u] = h2{(_Float16)0.0f, (_Float16)0.0f};
        if (j < 47) {
#pragma unroll
            for (int g = 0; g < 4; ++g) loadw47h(w[g], &rWhh0[(g * 47 + j) * 47]);
        }
        float c0 = 0.f;
        __syncthreads();
        for (int i = 0; i < TOTAL; ++i) {
            const int s = i - 8;
            float hv = 0.0f;
            if (s >= 0 && s < T_STEPS && j < 47) {
                float4 pa = *(const float4*)&pAring[s & 15][j * 4];   // off-chain, issue first
                h2 in[24];
                unpackh(in, &h0f16[(s - 1) & 15][0]);                  // the chain
                float4 pre = dot4h_r(in, w, pa);
                float iv = sig_f(pre.x), fv = sig_f(pre.y);
                float gv = tanh_f(pre.z), ov = sig_f(pre.w);
                c0 = fmaf(fv, c0, iv * gv);
                hv = ov * tanh_f(c0);
            }
            float hn = dppf<DPP_PAIR>(hv);     // even lane gets odd partner's h
            if (s >= 0 && s < T_STEPS && j < 47 && !(j & 1)) {
                h0f16[s & 15][j >> 1] = __builtin_bit_cast(h2, __builtin_amdgcn_cvt_pkrtz(hv, hn));
            }
            if ((i & 7) == 7) LDS_BARRIER();
        }
    } else if (wid == 2) {
        // ===== XB (lag 16): pB(s) = Wih1*h0(s)+b1, f16 dots =====
        h2 w[4][24]; float4 bias = {0, 0, 0, 0};
#pragma unroll
        for (int g = 0; g < 4; ++g)
#pragma unroll
            for (int u = 0; u < 24; ++u) w[g][u] = h2{(_Float16)0.0f, (_Float16)0.0f};
        if (j < 47) {
            float bb[4];
#pragma unroll
            for (int g = 0; g < 4; ++g) {
                loadw47h(w[g], &rWih1[(g * 47 + j) * 47]);
                bb[g] = rbih1[g * 47 + j] + rbhh1[g * 47 + j];
            }
            bias = {bb[0], bb[1], bb[2], bb[3]};
        }
        __syncthreads();
        for (int i = 0; i < TOTAL; ++i) {
            const int s = i - 16;
            if (s >= 0 && s < T_STEPS && j < 47) {
                h2 in[24];
                unpackh(in, &h0f16[s & 15][0]);
                float4 pre = dot4h_r(in, w, bias);
                *(float4*)&pBring[s & 15][j * 4] = pre;
            }
            if ((i & 7) == 7) LDS_BARRIER();
        }
    } else if (wid == 3) {
        // ===== HB (lag 24): h1(s) = cell(pB(s) + Whh1*h1(s-1)), f16 dots =====
        h2 w[4][24];
#pragma unroll
        for (int g = 0; g < 4; ++g)
#pragma unroll
            for (int u = 0; u < 24; ++u) w[g][u] = h2{(_Float16)0.0f, (_Float16)0.0f};
        if (j < 47) {
#pragma unroll
            for (int g = 0; g < 4; ++g) loadw47h(w[g], &rWhh1[(g * 47 + j) * 47]);
        }
        float c1 = 0.f;
        __syncthreads();
        for (int i = 0; i < TOTAL; ++i) {
            const int s = i - 24;
            float hv = 0.0f;
            if (s >= 0 && s < T_STEPS && j < 47) {
                float4 pb = *(const float4*)&pBring[s & 15][j * 4];   // off-chain, issue first
                h2 in[24];
                unpackh(in, &h1f16[(s - 1) & 15][0]);                  // the chain
                float4 pre = dot4h_r(in, w, pb);
                float iv = sig_f(pre.x), fv = sig_f(pre.y);
                float gv = tanh_f(pre.z), ov = sig_f(pre.w);
                c1 = fmaf(fv, c1, iv * gv);
                hv = ov * tanh_f(c1);
                tring[s & 63][64 + j] = hv;    // f32 for TT
                r_out[((size_t)b * T_STEPS + s) * 47 + j] = hv;
            }
            float hn = dppf<DPP_PAIR>(hv);
            if (s >= 0 && s < T_STEPS && j < 47 && !(j & 1)) {
                h1f16[s & 15][j >> 1] = __builtin_bit_cast(h2, __builtin_amdgcn_cvt_pkrtz(hv, hn));
            }
            if ((i & 7) == 7) LDS_BARRIER();
        }
    } else {
        // ===== TT (lag 32): t-RNN + x staging (8 ahead), f32 path =====
        const int u  = (l >> 2) & 1;
        const int g  = l & 3;
        const int hf = (l >> 3) & 1;
        const int R0 = g * 2 + u;
        f2 wt[24]; float wx48;
        if (hf == 0) {
            wx48 = 0.f;
#pragma unroll
            for (int k = 0; k < 24; ++k)
                wt[k] = f2{tWih0[R0 * 96 + 2 * k], tWih0[R0 * 96 + 2 * k + 1]};
        } else {
            wx48 = tWih0[R0 * 96 + 48];
#pragma unroll
            for (int k = 0; k < 23; ++k)
                wt[k] = f2{tWih0[R0 * 96 + 49 + 2 * k], tWih0[R0 * 96 + 49 + 2 * k + 1]};
            wt[23] = f2{tWih0[R0 * 96 + 95], 0.f};
        }
        const float bT0 = tbih0[R0] + tbhh0[R0];
        const float wh00 = tWhh0[R0 * 2 + 0], wh01 = tWhh0[R0 * 2 + 1];
        const float wi10 = tWih1[R0 * 2 + 0], wi11 = tWih1[R0 * 2 + 1];
        const float wh10 = tWhh1[R0 * 2 + 0], wh11 = tWhh1[R0 * 2 + 1];
        const float bT1 = tbih1[R0] + tbhh1[R0];
        const bool isg = (g == 2);
        const float zm = isg ? 2.f : 1.f, sm = isg ? 2.f : 1.f, sa = isg ? -1.f : 0.f;
        float ht00 = 0.f, ht01 = 0.f, ct0u = 0.f;
        float ht10 = 0.f, ht11 = 0.f, ct1u = 0.f;

        float xa[4] = {0,0,0,0}, xb[4] = {0,0,0,0}, xc[4] = {0,0,0,0};
        if (l < 16) {
            for (int t = 0; t < 8; ++t) {
                float xv[4];
                loadx4(xv, x_r, x_t, xr_base + (size_t)t * 47, xt_base + (size_t)t * 2, l);
#pragma unroll
                for (int uu = 0; uu < 4; ++uu) {
                    int v = l + 16 * uu;
                    if (v < 49) tring[t][v] = xv[uu];
                }
            }
            loadx4(xa, x_r, x_t, xr_base + (size_t)8 * 47,  xt_base + (size_t)8 * 2,  l);
            loadx4(xb, x_r, x_t, xr_base + (size_t)9 * 47,  xt_base + (size_t)9 * 2,  l);
            loadx4(xc, x_r, x_t, xr_base + (size_t)10 * 47, xt_base + (size_t)10 * 2, l);
        }
        __syncthreads();

        for (int i = 0; i < TOTAL; ++i) {
            if (l < 16) {
                const int tw = i + 8;
                if (tw < T_STEPS) {
#pragma unroll
                    for (int uu = 0; uu < 4; ++uu) {
                        int v = l + 16 * uu;
                        if (v < 49) tring[tw & 63][v] = xa[uu];
                    }
                }
#pragma unroll
                for (int uu = 0; uu < 4; ++uu) { xa[uu] = xb[uu]; xb[uu] = xc[uu]; }
                int tl = i + 11;
                if (tl > T_STEPS - 1) tl = T_STEPS - 1;
                loadx4(xc, x_r, x_t, xr_base + (size_t)tl * 47, xt_base + (size_t)tl * 2, l);
            }
            const int s = i - 32;
            if (s >= 0 && s < T_STEPS) {
                f2 in[24];
                unpack12(in, (const float4*)&tring[s & 63][hf ? 64 : 0]);
                float x48 = tring[s & 63][48];
                // 4 sub-chains (depth 6)
                f2 av = {0, 0}, bv = {0, 0}, cv = {0, 0}, dv = {0, 0};
#pragma unroll
                for (int k = 0; k < 6; ++k) {
                    av = __builtin_elementwise_fma(wt[k],      in[k],      av);
                    bv = __builtin_elementwise_fma(wt[6 + k],  in[6 + k],  bv);
                    cv = __builtin_elementwise_fma(wt[12 + k], in[12 + k], cv);
                    dv = __builtin_elementwise_fma(wt[18 + k], in[18 + k], dv);
                }
                f2 sv = (av + bv) + (cv + dv);
                float part = fmaf(wx48, x48, sv.x + sv.y);
                float pre0 = part + dppf<DPP_ROR8>(part);
                pre0 += bT0 + wh00 * ht00 + wh01 * ht01;
                float a0 = gate_act(pre0, zm, sm, sa);
                float i0 = dppf<DPP_BCAST0>(a0);
                float f0 = dppf<DPP_BCAST1>(a0);
                float g0 = dppf<DPP_BCAST2>(a0);
                float o0 = dppf<DPP_BCAST3>(a0);
                ct0u = fmaf(f0, ct0u, i0 * g0);
                float htu = o0 * tanh_f(ct0u);
                float hto = dppf<DPP_ROR4>(htu);
                ht00 = (u == 0) ? htu : hto;
                ht01 = (u == 0) ? hto : htu;
                float pre1 = bT1 + wi10 * ht00 + wi11 * ht01 + wh10 * ht10 + wh11 * ht11;
                float a1 = gate_act(pre1, zm, sm, sa);
                float ji = dppf<DPP_BCAST0>(a1);
                float jf = dppf<DPP_BCAST1>(a1);
                float jg = dppf<DPP_BCAST2>(a1);
                float jo = dppf<DPP_BCAST3>(a1);
                ct1u = fmaf(jf, ct1u, ji * jg);
                float h1u = jo * tanh_f(ct1u);
                float h1o = dppf<DPP_ROR4>(h1u);
                ht10 = (u == 0) ? h1u : h1o;
                ht11 = (u == 0) ? h1o : h1u;
                if (l == 0) {
                    float2 tv = {ht10, ht11};
                    *reinterpret_cast<float2*>(&t_out[((size_t)b * T_STEPS + s) * 2]) = tv;
                }
            }
            if ((i & 7) == 7) LDS_BARRIER();
        }
    }
}

extern "C" void kernel_launch(void* const* d_in, const int* in_sizes, int n_in,
                              void* d_out, int out_size, void* d_ws, size_t ws_size,
                              hipStream_t stream) {
    const float* x_r   = (const float*)d_in[0];
    const float* x_t   = (const float*)d_in[1];
    const float* rWih0 = (const float*)d_in[2];
    const float* rWhh0 = (const float*)d_in[3];
    const float* rbih0 = (const float*)d_in[4];
    const float* rbhh0 = (const float*)d_in[5];
    const float* rWih1 = (const float*)d_in[6];
    const float* rWhh1 = (const float*)d_in[7];
    const float* rbih1 = (const float*)d_in[8];
    const float* rbhh1 = (const float*)d_in[9];
    const float* tWih0 = (const float*)d_in[10];
    const float* tWhh0 = (const float*)d_in[11];
    const float* tbih0 = (const float*)d_in[12];
    const float* tbhh0 = (const float*)d_in[13];
    const float* tWih1 = (const float*)d_in[14];
    const float* tWhh1 = (const float*)d_in[15];
    const float* tbih1 = (const float*)d_in[16];
    const float* tbhh1 = (const float*)d_in[17];

    float* r_out = (float*)d_out;
    float* t_out = r_out + (size_t)256 * T_STEPS * 47;

    hipLaunchKernelGGL(adrnn_fused, dim3(256), dim3(320), 0, stream,
                       x_r, x_t, rWih0, rWhh0, rbih0, rbhh0, rWih1, rWhh1, rbih1, rbhh1,
                       tWih0, tWhh0, tbih0, tbhh0, tWih1, tWhh1, tbih1, tbhh1,
                       r_out, t_out);
}

// Round 14
// 1512.216 us; speedup vs baseline: 1.0027x; 1.0027x over previous
//
#include <hip/hip_runtime.h>

#define T_STEPS 2048
#define TOTAL   2080   // T_STEPS + 32 (deepest lag)

typedef float f2 __attribute__((ext_vector_type(2)));
typedef _Float16 h2 __attribute__((ext_vector_type(2)));

__device__ __forceinline__ float fast_rcp(float x) { return __builtin_amdgcn_rcpf(x); }

__device__ __forceinline__ float sig_f(float x) {
    return fast_rcp(1.0f + __expf(-x));
}
__device__ __forceinline__ float tanh_f(float x) {
    float e = __expf(-2.0f * x);
    return fmaf(2.0f, fast_rcp(1.0f + e), -1.0f);
}
__device__ __forceinline__ float gate_act(float x, float zm, float sm, float sa) {
    float e = __expf(-x * zm);
    return fmaf(fast_rcp(1.0f + e), sm, sa);
}

// f16 dot2 with f32 accumulate
#if __has_builtin(__builtin_amdgcn_fdot2)
#define FDOT2(a, b, c) __builtin_amdgcn_fdot2((a), (b), (c), false)
#else
__device__ __forceinline__ float FDOT2(h2 a, h2 b, float c) {
    return fmaf((float)a.x, (float)b.x, fmaf((float)a.y, (float)b.y, c));
}
#endif

// Drain ONLY lgkmcnt (LDS) before barrier — never vmcnt (R7 win).
#define LDS_BARRIER() asm volatile("s_waitcnt lgkmcnt(0)\n\ts_barrier" ::: "memory")

#define DPP_BCAST0 0x00
#define DPP_BCAST1 0x55
#define DPP_BCAST2 0xAA
#define DPP_BCAST3 0xFF
#define DPP_PAIR   0xF5    // quad_perm [1,1,3,3]: even lane gets odd partner's value
#define DPP_ROR4   0x124
#define DPP_ROR8   0x128
template<int CTRL>
__device__ __forceinline__ float dppf(float x) {
    int r = __builtin_amdgcn_update_dpp(0, __builtin_bit_cast(int, x), CTRL, 0xF, 0xF, true);
    return __builtin_bit_cast(float, r);
}

__device__ __forceinline__ void loadx4(float (&dst)[4], const float* __restrict__ x_r,
                                       const float* __restrict__ x_t,
                                       size_t xrb, size_t xtb, int l) {
#pragma unroll
    for (int u = 0; u < 4; ++u) {
        int v = l + 16 * u;
        dst[u] = (v < 47) ? x_r[xrb + v] : ((v < 49) ? x_t[xtb + (v - 47)] : 0.0f);
    }
}

__device__ __forceinline__ void unpack12(f2 (&in)[24], const float4* __restrict__ r4) {
#pragma unroll
    for (int u = 0; u < 12; ++u) {
        float4 v = r4[u];
        in[2 * u]     = f2{v.x, v.y};
        in[2 * u + 1] = f2{v.z, v.w};
    }
}

// 48 f16 (24 h2) as 6 ds_read_b128
__device__ __forceinline__ void unpackh(h2 (&in)[24], const h2* __restrict__ row) {
    const float4* q = (const float4*)row;
#pragma unroll
    for (int k = 0; k < 6; ++k) {
        float4 v = q[k];
        in[4 * k + 0] = __builtin_bit_cast(h2, v.x);
        in[4 * k + 1] = __builtin_bit_cast(h2, v.y);
        in[4 * k + 2] = __builtin_bit_cast(h2, v.z);
        in[4 * k + 3] = __builtin_bit_cast(h2, v.w);
    }
}

// Reassociated: 4 independent sub-chains (depth 6) per gate -> ~64cy latency
// instead of one 24-deep chain (~192cy). The recurrent waves' step time is
// dependent-chain-bound, so chain depth is the lever.
__device__ __forceinline__ float4 dot4h_r(const h2 (&in)[24], const h2 (&w)[4][24], float4 init) {
    float a00 = init.x, a01 = 0.f, a02 = 0.f, a03 = 0.f;
    float a10 = init.y, a11 = 0.f, a12 = 0.f, a13 = 0.f;
    float a20 = init.z, a21 = 0.f, a22 = 0.f, a23 = 0.f;
    float a30 = init.w, a31 = 0.f, a32 = 0.f, a33 = 0.f;
#pragma unroll
    for (int k = 0; k < 6; ++k) {
        a00 = FDOT2(w[0][k],      in[k],      a00);
        a01 = FDOT2(w[0][6 + k],  in[6 + k],  a01);
        a02 = FDOT2(w[0][12 + k], in[12 + k], a02);
        a03 = FDOT2(w[0][18 + k], in[18 + k], a03);
        a10 = FDOT2(w[1][k],      in[k],      a10);
        a11 = FDOT2(w[1][6 + k],  in[6 + k],  a11);
        a12 = FDOT2(w[1][12 + k], in[12 + k], a12);
        a13 = FDOT2(w[1][18 + k], in[18 + k], a13);
        a20 = FDOT2(w[2][k],      in[k],      a20);
        a21 = FDOT2(w[2][6 + k],  in[6 + k],  a21);
        a22 = FDOT2(w[2][12 + k], in[12 + k], a22);
        a23 = FDOT2(w[2][18 + k], in[18 + k], a23);
        a30 = FDOT2(w[3][k],      in[k],      a30);
        a31 = FDOT2(w[3][6 + k],  in[6 + k],  a31);
        a32 = FDOT2(w[3][12 + k], in[12 + k], a32);
        a33 = FDOT2(w[3][18 + k], in[18 + k], a33);
    }
    return float4{(a00 + a01) + (a02 + a03), (a10 + a11) + (a12 + a13),
                  (a20 + a21) + (a22 + a23), (a30 + a31) + (a32 + a33)};
}

// load a 47-col f32 weight row as 24 packed-f16 pairs (pad last to 0)
__device__ __forceinline__ void loadw47h(h2 (&w)[24], const float* __restrict__ src) {
#pragma unroll
    for (int u = 0; u < 23; ++u)
        w[u] = h2{(_Float16)src[2 * u], (_Float16)src[2 * u + 1]};
    w[23] = h2{(_Float16)src[46], (_Float16)0.0f};
}

__global__ __launch_bounds__(320) void adrnn_fused(
    const float* __restrict__ x_r, const float* __restrict__ x_t,
    const float* __restrict__ rWih0, const float* __restrict__ rWhh0,
    const float* __restrict__ rbih0, const float* __restrict__ rbhh0,
    const float* __restrict__ rWih1, const float* __restrict__ rWhh1,
    const float* __restrict__ rbih1, const float* __restrict__ rbhh1,
    const float* __restrict__ tWih0, const float* __restrict__ tWhh0,
    const float* __restrict__ tbih0, const float* __restrict__ tbhh0,
    const float* __restrict__ tWih1, const float* __restrict__ tWhh1,
    const float* __restrict__ tbih1, const float* __restrict__ tbhh1,
    float* __restrict__ r_out, float* __restrict__ t_out)
{
    __shared__ __align__(16) float tring[64][112]; // [x 0..48 | pad | h1 64..110 | pad]
    __shared__ __align__(16) h2 h0f16[16][32];     // h0(s), 24 h2 used
    __shared__ __align__(16) h2 h1f16[16][32];     // h1(s) for HB recurrence
    __shared__ __align__(16) float pAring[16][192];
    __shared__ __align__(16) float pBring[16][192];

    const int tid = threadIdx.x;
    const int wid = tid >> 6;
    const int l   = tid & 63;
    const int j   = l;
    const int b = blockIdx.x;
    const size_t xr_base = (size_t)b * T_STEPS * 47;
    const size_t xt_base = (size_t)b * T_STEPS * 2;

    if (tid < 256) {
        for (int k = tid; k < 64 * 48; k += 256) tring[k / 48][64 + (k % 48)] = 0.0f;
        for (int k = tid; k < 16 * 32; k += 256) {
            h0f16[k >> 5][k & 31] = h2{(_Float16)0.0f, (_Float16)0.0f};
            h1f16[k >> 5][k & 31] = h2{(_Float16)0.0f, (_Float16)0.0f};
        }
    }

    if (wid == 0) {
        // ===== XA (lag 0): pA(i) = Wih0*x(i)+b0, f32 path =====
        f2 w[4][24]; float w48[4]; float4 bias = {0, 0, 0, 0};
#pragma unroll
        for (int g = 0; g < 4; ++g) { w48[g] = 0.f;
#pragma unroll
            for (int u = 0; u < 24; ++u) w[g][u] = f2{0.f, 0.f}; }
        if (j < 47) {
            float bb[4];
#pragma unroll
            for (int g = 0; g < 4; ++g) {
                const int row = g * 47 + j;
#pragma unroll
                for (int u = 0; u < 24; ++u)
                    w[g][u] = f2{rWih0[row * 49 + 2 * u], rWih0[row * 49 + 2 * u + 1]};
                w48[g] = rWih0[row * 49 + 48];
                bb[g] = rbih0[row] + rbhh0[row];
            }
            bias = {bb[0], bb[1], bb[2], bb[3]};
        }
        __syncthreads();
        for (int i = 0; i < TOTAL; ++i) {
            if (i < T_STEPS && j < 47) {
                f2 in[24];
                unpack12(in, (const float4*)&tring[i & 63][0]);
                float x48 = tring[i & 63][48];
                // 2 sub-chains per gate (depth 12)
                f2 a0 = f2{bias.x, 0.f}, b0v = {0, 0};
                f2 a1 = f2{bias.y, 0.f}, b1v = {0, 0};
                f2 a2 = f2{bias.z, 0.f}, b2v = {0, 0};
                f2 a3 = f2{bias.w, 0.f}, b3v = {0, 0};
#pragma unroll
                for (int u = 0; u < 12; ++u) {
                    a0  = __builtin_elementwise_fma(w[0][u],      in[u],      a0);
                    b0v = __builtin_elementwise_fma(w[0][12 + u], in[12 + u], b0v);
                    a1  = __builtin_elementwise_fma(w[1][u],      in[u],      a1);
                    b1v = __builtin_elementwise_fma(w[1][12 + u], in[12 + u], b1v);
                    a2  = __builtin_elementwise_fma(w[2][u],      in[u],      a2);
                    b2v = __builtin_elementwise_fma(w[2][12 + u], in[12 + u], b2v);
                    a3  = __builtin_elementwise_fma(w[3][u],      in[u],      a3);
                    b3v = __builtin_elementwise_fma(w[3][12 + u], in[12 + u], b3v);
                }
                f2 s0 = a0 + b0v, s1 = a1 + b1v, s2 = a2 + b2v, s3 = a3 + b3v;
                float4 out;
                out.x = fmaf(w48[0], x48, s0.x + s0.y);
                out.y = fmaf(w48[1], x48, s1.x + s1.y);
                out.z = fmaf(w48[2], x48, s2.x + s2.y);
                out.w = fmaf(w48[3], x48, s3.x + s3.y);
                *(float4*)&pAring[i & 15][j * 4] = out;
            }
            if ((i & 7) == 7) LDS_BARRIER();
        }
    } else if (wid == 1) {
        // ===== HA (lag 8): h0(s) = cell(pA(s) + Whh0*h0(s-1)), f16 dots =====
        h2 w[4][24];
#pragma unroll
        for (int g = 0; g < 4; ++g)
#pragma unroll
            for (int u = 0; u < 24; ++u) w[g][u] = h2{(_Float16)0.0f, (_Float16)0.0f};
        if (j < 47) {
#pragma unroll
            for (int g = 0; g < 4; ++g) loadw47h(w[g], &rWhh0[(g * 47 + j) * 47]);
        }
        float c0 = 0.f;
        __syncthreads();
        for (int i = 0; i < TOTAL; ++i) {
            const int s = i - 8;
            float hv = 0.0f;
            if (s >= 0 && s < T_STEPS && j < 47) {
                float4 pa = *(const float4*)&pAring[s & 15][j * 4];   // off-chain, issue first
                h2 in[24];
                unpackh(in, &h0f16[(s - 1) & 15][0]);                  // the chain
                float4 pre = dot4h_r(in, w, pa);
                float iv = sig_f(pre.x), fv = sig_f(pre.y);
                float gv = tanh_f(pre.z), ov = sig_f(pre.w);
                c0 = fmaf(fv, c0, iv * gv);
                hv = ov * tanh_f(c0);
            }
            float hn = dppf<DPP_PAIR>(hv);     // even lane gets odd partner's h
            if (s >= 0 && s < T_STEPS && j < 47 && !(j & 1)) {
                h0f16[s & 15][j >> 1] = __builtin_bit_cast(h2, __builtin_amdgcn_cvt_pkrtz(hv, hn));
            }
            if ((i & 7) == 7) LDS_BARRIER();
        }
    } else if (wid == 2) {
        // ===== XB (lag 16): pB(s) = Wih1*h0(s)+b1, f16 dots =====
        h2 w[4][24]; float4 bias = {0, 0, 0, 0};
#pragma unroll
        for (int g = 0; g < 4; ++g)
#pragma unroll
            for (int u = 0; u < 24; ++u) w[g][u] = h2{(_Float16)0.0f, (_Float16)0.0f};
        if (j < 47) {
            float bb[4];
#pragma unroll
            for (int g = 0; g < 4; ++g) {
                loadw47h(w[g], &rWih1[(g * 47 + j) * 47]);
                bb[g] = rbih1[g * 47 + j] + rbhh1[g * 47 + j];
            }
            bias = {bb[0], bb[1], bb[2], bb[3]};
        }
        __syncthreads();
        for (int i = 0; i < TOTAL; ++i) {
            const int s = i - 16;
            if (s >= 0 && s < T_STEPS && j < 47) {
                h2 in[24];
                unpackh(in, &h0f16[s & 15][0]);
                float4 pre = dot4h_r(in, w, bias);
                *(float4*)&pBring[s & 15][j * 4] = pre;
            }
            if ((i & 7) == 7) LDS_BARRIER();
        }
    } else if (wid == 3) {
        // ===== HB (lag 24): h1(s) = cell(pB(s) + Whh1*h1(s-1)), f16 dots =====
        h2 w[4][24];
#pragma unroll
        for (int g = 0; g < 4; ++g)
#pragma unroll
            for (int u = 0; u < 24; ++u) w[g][u] = h2{(_Float16)0.0f, (_Float16)0.0f};
        if (j < 47) {
#pragma unroll
            for (int g = 0; g < 4; ++g) loadw47h(w[g], &rWhh1[(g * 47 + j) * 47]);
        }
        float c1 = 0.f;
        __syncthreads();
        for (int i = 0; i < TOTAL; ++i) {
            const int s = i - 24;
            float hv = 0.0f;
            if (s >= 0 && s < T_STEPS && j < 47) {
                float4 pb = *(const float4*)&pBring[s & 15][j * 4];   // off-chain, issue first
                h2 in[24];
                unpackh(in, &h1f16[(s - 1) & 15][0]);                  // the chain
                float4 pre = dot4h_r(in, w, pb);
                float iv = sig_f(pre.x), fv = sig_f(pre.y);
                float gv = tanh_f(pre.z), ov = sig_f(pre.w);
                c1 = fmaf(fv, c1, iv * gv);
                hv = ov * tanh_f(c1);
                tring[s & 63][64 + j] = hv;    // f32 for TT
                r_out[((size_t)b * T_STEPS + s) * 47 + j] = hv;
            }
            float hn = dppf<DPP_PAIR>(hv);
            if (s >= 0 && s < T_STEPS && j < 47 && !(j & 1)) {
                h1f16[s & 15][j >> 1] = __builtin_bit_cast(h2, __builtin_amdgcn_cvt_pkrtz(hv, hn));
            }
            if ((i & 7) == 7) LDS_BARRIER();
        }
    } else {
        // ===== TT (lag 32): t-RNN + x staging (8 ahead), f32 path =====
        const int u  = (l >> 2) & 1;
        const int g  = l & 3;
        const int hf = (l >> 3) & 1;
        const int R0 = g * 2 + u;
        f2 wt[24]; float wx48;
        if (hf == 0) {
            wx48 = 0.f;
#pragma unroll
            for (int k = 0; k < 24; ++k)
                wt[k] = f2{tWih0[R0 * 96 + 2 * k], tWih0[R0 * 96 + 2 * k + 1]};
        } else {
            wx48 = tWih0[R0 * 96 + 48];
#pragma unroll
            for (int k = 0; k < 23; ++k)
                wt[k] = f2{tWih0[R0 * 96 + 49 + 2 * k], tWih0[R0 * 96 + 49 + 2 * k + 1]};
            wt[23] = f2{tWih0[R0 * 96 + 95], 0.f};
        }
        const float bT0 = tbih0[R0] + tbhh0[R0];
        const float wh00 = tWhh0[R0 * 2 + 0], wh01 = tWhh0[R0 * 2 + 1];
        const float wi10 = tWih1[R0 * 2 + 0], wi11 = tWih1[R0 * 2 + 1];
        const float wh10 = tWhh1[R0 * 2 + 0], wh11 = tWhh1[R0 * 2 + 1];
        const float bT1 = tbih1[R0] + tbhh1[R0];
        const bool isg = (g == 2);
        const float zm = isg ? 2.f : 1.f, sm = isg ? 2.f : 1.f, sa = isg ? -1.f : 0.f;
        float ht00 = 0.f, ht01 = 0.f, ct0u = 0.f;
        float ht10 = 0.f, ht11 = 0.f, ct1u = 0.f;

        float xa[4] = {0,0,0,0}, xb[4] = {0,0,0,0}, xc[4] = {0,0,0,0};
        if (l < 16) {
            for (int t = 0; t < 8; ++t) {
                float xv[4];
                loadx4(xv, x_r, x_t, xr_base + (size_t)t * 47, xt_base + (size_t)t * 2, l);
#pragma unroll
                for (int uu = 0; uu < 4; ++uu) {
                    int v = l + 16 * uu;
                    if (v < 49) tring[t][v] = xv[uu];
                }
            }
            loadx4(xa, x_r, x_t, xr_base + (size_t)8 * 47,  xt_base + (size_t)8 * 2,  l);
            loadx4(xb, x_r, x_t, xr_base + (size_t)9 * 47,  xt_base + (size_t)9 * 2,  l);
            loadx4(xc, x_r, x_t, xr_base + (size_t)10 * 47, xt_base + (size_t)10 * 2, l);
        }
        __syncthreads();

        for (int i = 0; i < TOTAL; ++i) {
            if (l < 16) {
                const int tw = i + 8;
                if (tw < T_STEPS) {
#pragma unroll
                    for (int uu = 0; uu < 4; ++uu) {
                        int v = l + 16 * uu;
                        if (v < 49) tring[tw & 63][v] = xa[uu];
                    }
                }
#pragma unroll
                for (int uu = 0; uu < 4; ++uu) { xa[uu] = xb[uu]; xb[uu] = xc[uu]; }
                int tl = i + 11;
                if (tl > T_STEPS - 1) tl = T_STEPS - 1;
                loadx4(xc, x_r, x_t, xr_base + (size_t)tl * 47, xt_base + (size_t)tl * 2, l);
            }
            const int s = i - 32;
            if (s >= 0 && s < T_STEPS) {
                f2 in[24];
                unpack12(in, (const float4*)&tring[s & 63][hf ? 64 : 0]);
                float x48 = tring[s & 63][48];
                // 4 sub-chains (depth 6)
                f2 av = {0, 0}, bv = {0, 0}, cv = {0, 0}, dv = {0, 0};
#pragma unroll
                for (int k = 0; k < 6; ++k) {
                    av = __builtin_elementwise_fma(wt[k],      in[k],      av);
                    bv = __builtin_elementwise_fma(wt[6 + k],  in[6 + k],  bv);
                    cv = __builtin_elementwise_fma(wt[12 + k], in[12 + k], cv);
                    dv = __builtin_elementwise_fma(wt[18 + k], in[18 + k], dv);
                }
                f2 sv = (av + bv) + (cv + dv);
                float part = fmaf(wx48, x48, sv.x + sv.y);
                float pre0 = part + dppf<DPP_ROR8>(part);
                pre0 += bT0 + wh00 * ht00 + wh01 * ht01;
                float a0 = gate_act(pre0, zm, sm, sa);
                float i0 = dppf<DPP_BCAST0>(a0);
                float f0 = dppf<DPP_BCAST1>(a0);
                float g0 = dppf<DPP_BCAST2>(a0);
                float o0 = dppf<DPP_BCAST3>(a0);
                ct0u = fmaf(f0, ct0u, i0 * g0);
                float htu = o0 * tanh_f(ct0u);
                float hto = dppf<DPP_ROR4>(htu);
                ht00 = (u == 0) ? htu : hto;
                ht01 = (u == 0) ? hto : htu;
                float pre1 = bT1 + wi10 * ht00 + wi11 * ht01 + wh10 * ht10 + wh11 * ht11;
                float a1 = gate_act(pre1, zm, sm, sa);
                float ji = dppf<DPP_BCAST0>(a1);
                float jf = dppf<DPP_BCAST1>(a1);
                float jg = dppf<DPP_BCAST2>(a1);
                float jo = dppf<DPP_BCAST3>(a1);
                ct1u = fmaf(jf, ct1u, ji * jg);
                float h1u = jo * tanh_f(ct1u);
                float h1o = dppf<DPP_ROR4>(h1u);
                ht10 = (u == 0) ? h1u : h1o;
                ht11 = (u == 0) ? h1o : h1u;
                if (l == 0) {
                    float2 tv = {ht10, ht11};
                    *reinterpret_cast<float2*>(&t_out[((size_t)b * T_STEPS + s) * 2]) = tv;
                }
            }
            if ((i & 7) == 7) LDS_BARRIER();
        }
    }
}

extern "C" void kernel_launch(void* const* d_in, const int* in_sizes, int n_in,
                              void* d_out, int out_size, void* d_ws, size_t ws_size,
                              hipStream_t stream) {
    const float* x_r   = (const float*)d_in[0];
    const float* x_t   = (const float*)d_in[1];
    const float* rWih0 = (const float*)d_in[2];
    const float* rWhh0 = (const float*)d_in[3];
    const float* rbih0 = (const float*)d_in[4];
    const float* rbhh0 = (const float*)d_in[5];
    const float* rWih1 = (const float*)d_in[6];
    const float* rWhh1 = (const float*)d_in[7];
    const float* rbih1 = (const float*)d_in[8];
    const float* rbhh1 = (const float*)d_in[9];
    const float* tWih0 = (const float*)d_in[10];
    const float* tWhh0 = (const float*)d_in[11];
    const float* tbih0 = (const float*)d_in[12];
    const float* tbhh0 = (const float*)d_in[13];
    const float* tWih1 = (const float*)d_in[14];
    const float* tWhh1 = (const float*)d_in[15];
    const float* tbih1 = (const float*)d_in[16];
    const float* tbhh1 = (const float*)d_in[17];

    float* r_out = (float*)d_out;
    float* t_out = r_out + (size_t)256 * T_STEPS * 47;

    hipLaunchKernelGGL(adrnn_fused, dim3(256), dim3(320), 0, stream,
                       x_r, x_t, rWih0, rWhh0, rbih0, rbhh0, rWih1, rWhh1, rbih1, rbhh1,
                       tWih0, tWhh0, tbih0, tbhh0, tWih1, tWhh1, tbih1, tbhh1,
                       r_out, t_out);
}

// Round 15
// 1451.646 us; speedup vs baseline: 1.0445x; 1.0417x over previous
//
#include <hip/hip_runtime.h>

#define T_STEPS 2048
#define TOTAL   2080   // T_STEPS + 32 (deepest lag: TT)

typedef float f2 __attribute__((ext_vector_type(2)));
typedef _Float16 h2 __attribute__((ext_vector_type(2)));

__device__ __forceinline__ float fast_rcp(float x) { return __builtin_amdgcn_rcpf(x); }

__device__ __forceinline__ float sig_f(float x) { return fast_rcp(1.0f + __expf(-x)); }
__device__ __forceinline__ float tanh_f(float x) {
    float e = __expf(-2.0f * x);
    return fmaf(2.0f, fast_rcp(1.0f + e), -1.0f);
}
__device__ __forceinline__ float gate_act(float x, float zm, float sm, float sa) {
    float e = __expf(-x * zm);
    return fmaf(fast_rcp(1.0f + e), sm, sa);
}

#if __has_builtin(__builtin_amdgcn_fdot2)
#define FDOT2(a, b, c) __builtin_amdgcn_fdot2((a), (b), (c), false)
#else
__device__ __forceinline__ float FDOT2(h2 a, h2 b, float c) {
    return fmaf((float)a.x, (float)b.x, fmaf((float)a.y, (float)b.y, c));
}
#endif

// Drain ONLY lgkmcnt (LDS) before barrier — never vmcnt (R7 win).
#define LDS_BARRIER() asm volatile("s_waitcnt lgkmcnt(0)\n\ts_barrier" ::: "memory")

#define DPP_BCAST0 0x00
#define DPP_BCAST1 0x55
#define DPP_BCAST2 0xAA
#define DPP_BCAST3 0xFF
#define DPP_PAIR   0xF5
#define DPP_ROR4   0x124
#define DPP_ROR8   0x128
template<int CTRL>
__device__ __forceinline__ float dppf(float x) {
    int r = __builtin_amdgcn_update_dpp(0, __builtin_bit_cast(int, x), CTRL, 0xF, 0xF, true);
    return __builtin_bit_cast(float, r);
}

__device__ __forceinline__ void loadx4(float (&dst)[4], const float* __restrict__ x_r,
                                       const float* __restrict__ x_t,
                                       size_t xrb, size_t xtb, int l) {
#pragma unroll
    for (int u = 0; u < 4; ++u) {
        int v = l + 16 * u;
        dst[u] = (v < 47) ? x_r[xrb + v] : ((v < 49) ? x_t[xtb + (v - 47)] : 0.0f);
    }
}

__device__ __forceinline__ void unpack12(f2 (&in)[24], const float4* __restrict__ r4) {
#pragma unroll
    for (int u = 0; u < 12; ++u) {
        float4 v = r4[u];
        in[2 * u]     = f2{v.x, v.y};
        in[2 * u + 1] = f2{v.z, v.w};
    }
}

__device__ __forceinline__ void unpackh(h2 (&in)[24], const h2* __restrict__ row) {
    const float4* q = (const float4*)row;
#pragma unroll
    for (int k = 0; k < 6; ++k) {
        float4 v = q[k];
        in[4 * k + 0] = __builtin_bit_cast(h2, v.x);
        in[4 * k + 1] = __builtin_bit_cast(h2, v.y);
        in[4 * k + 2] = __builtin_bit_cast(h2, v.z);
        in[4 * k + 3] = __builtin_bit_cast(h2, v.w);
    }
}

// chained (R11 form — R14's reassociation regressed; dot is issue-bound)
__device__ __forceinline__ float4 dot4h(const h2 (&in)[24], const h2 (&w)[4][24], float4 init) {
    float a0 = init.x, a1 = init.y, a2 = init.z, a3 = init.w;
#pragma unroll
    for (int u = 0; u < 24; ++u) {
        a0 = FDOT2(w[0][u], in[u], a0);
        a1 = FDOT2(w[1][u], in[u], a1);
        a2 = FDOT2(w[2][u], in[u], a2);
        a3 = FDOT2(w[3][u], in[u], a3);
    }
    return float4{a0, a1, a2, a3};
}

__device__ __forceinline__ void loadw47h(h2 (&w)[24], const float* __restrict__ src) {
#pragma unroll
    for (int u = 0; u < 23; ++u)
        w[u] = h2{(_Float16)src[2 * u], (_Float16)src[2 * u + 1]};
    w[23] = h2{(_Float16)src[46], (_Float16)0.0f};
}

// 4 waves = one per SIMD (no SIMD sharing — the R14 phantom-theory test):
// W0 = XA + x staging, W1 = HA, W2 = XB + TT, W3 = HB.
__global__ __launch_bounds__(256) void adrnn_fused(
    const float* __restrict__ x_r, const float* __restrict__ x_t,
    const float* __restrict__ rWih0, const float* __restrict__ rWhh0,
    const float* __restrict__ rbih0, const float* __restrict__ rbhh0,
    const float* __restrict__ rWih1, const float* __restrict__ rWhh1,
    const float* __restrict__ rbih1, const float* __restrict__ rbhh1,
    const float* __restrict__ tWih0, const float* __restrict__ tWhh0,
    const float* __restrict__ tbih0, const float* __restrict__ tbhh0,
    const float* __restrict__ tWih1, const float* __restrict__ tWhh1,
    const float* __restrict__ tbih1, const float* __restrict__ tbhh1,
    float* __restrict__ r_out, float* __restrict__ t_out)
{
    __shared__ __align__(16) float tring[64][112]; // [x 0..48 | pad | h1 64..110 | pad]
    __shared__ __align__(16) h2 h0f16[16][32];
    __shared__ __align__(16) h2 h1f16[16][32];
    __shared__ __align__(16) float pAring[16][192];
    __shared__ __align__(16) float pBring[16][192];

    const int tid = threadIdx.x;
    const int wid = tid >> 6;
    const int l   = tid & 63;
    const int j   = l;
    const int b = blockIdx.x;
    const size_t xr_base = (size_t)b * T_STEPS * 47;
    const size_t xt_base = (size_t)b * T_STEPS * 2;

    {
        for (int k = tid; k < 64 * 48; k += 256) tring[k / 48][64 + (k % 48)] = 0.0f;
        for (int k = tid; k < 16 * 32; k += 256) {
            h0f16[k >> 5][k & 31] = h2{(_Float16)0.0f, (_Float16)0.0f};
            h1f16[k >> 5][k & 31] = h2{(_Float16)0.0f, (_Float16)0.0f};
        }
    }

    if (wid == 0) {
        // ===== W0: XA (lag 0) + x staging (8 ahead) =====
        f2 w[4][24]; float w48[4]; float4 bias = {0, 0, 0, 0};
#pragma unroll
        for (int g = 0; g < 4; ++g) { w48[g] = 0.f;
#pragma unroll
            for (int u = 0; u < 24; ++u) w[g][u] = f2{0.f, 0.f}; }
        if (j < 47) {
            float bb[4];
#pragma unroll
            for (int g = 0; g < 4; ++g) {
                const int row = g * 47 + j;
#pragma unroll
                for (int u = 0; u < 24; ++u)
                    w[g][u] = f2{rWih0[row * 49 + 2 * u], rWih0[row * 49 + 2 * u + 1]};
                w48[g] = rWih0[row * 49 + 48];
                bb[g] = rbih0[row] + rbhh0[row];
            }
            bias = {bb[0], bb[1], bb[2], bb[3]};
        }
        // staging prologue: x(0..7) -> tring; prefetch regs x(8),x(9),x(10)
        float xa[4] = {0,0,0,0}, xb[4] = {0,0,0,0}, xc[4] = {0,0,0,0};
        if (l < 16) {
            for (int t = 0; t < 8; ++t) {
                float xv[4];
                loadx4(xv, x_r, x_t, xr_base + (size_t)t * 47, xt_base + (size_t)t * 2, l);
#pragma unroll
                for (int uu = 0; uu < 4; ++uu) {
                    int v = l + 16 * uu;
                    if (v < 49) tring[t][v] = xv[uu];
                }
            }
            loadx4(xa, x_r, x_t, xr_base + (size_t)8 * 47,  xt_base + (size_t)8 * 2,  l);
            loadx4(xb, x_r, x_t, xr_base + (size_t)9 * 47,  xt_base + (size_t)9 * 2,  l);
            loadx4(xc, x_r, x_t, xr_base + (size_t)10 * 47, xt_base + (size_t)10 * 2, l);
        }
        __syncthreads();
        for (int i = 0; i < TOTAL; ++i) {
            if (i < T_STEPS && j < 47) {
                f2 in[24];
                unpack12(in, (const float4*)&tring[i & 63][0]);
                float x48 = tring[i & 63][48];
                f2 a0 = f2{bias.x, 0.f}, b0v = {0, 0};
                f2 a1 = f2{bias.y, 0.f}, b1v = {0, 0};
                f2 a2 = f2{bias.z, 0.f}, b2v = {0, 0};
                f2 a3 = f2{bias.w, 0.f}, b3v = {0, 0};
#pragma unroll
                for (int u = 0; u < 12; ++u) {
                    a0  = __builtin_elementwise_fma(w[0][u],      in[u],      a0);
                    b0v = __builtin_elementwise_fma(w[0][12 + u], in[12 + u], b0v);
                    a1  = __builtin_elementwise_fma(w[1][u],      in[u],      a1);
                    b1v = __builtin_elementwise_fma(w[1][12 + u], in[12 + u], b1v);
                    a2  = __builtin_elementwise_fma(w[2][u],      in[u],      a2);
                    b2v = __builtin_elementwise_fma(w[2][12 + u], in[12 + u], b2v);
                    a3  = __builtin_elementwise_fma(w[3][u],      in[u],      a3);
                    b3v = __builtin_elementwise_fma(w[3][12 + u], in[12 + u], b3v);
                }
                f2 s0 = a0 + b0v, s1 = a1 + b1v, s2 = a2 + b2v, s3 = a3 + b3v;
                float4 out;
                out.x = fmaf(w48[0], x48, s0.x + s0.y);
                out.y = fmaf(w48[1], x48, s1.x + s1.y);
                out.z = fmaf(w48[2], x48, s2.x + s2.y);
                out.w = fmaf(w48[3], x48, s3.x + s3.y);
                *(float4*)&pAring[i & 15][j * 4] = out;
            }
            if (l < 16) {
                const int tw = i + 8;
                if (tw < T_STEPS) {
#pragma unroll
                    for (int uu = 0; uu < 4; ++uu) {
                        int v = l + 16 * uu;
                        if (v < 49) tring[tw & 63][v] = xa[uu];
                    }
                }
#pragma unroll
                for (int uu = 0; uu < 4; ++uu) { xa[uu] = xb[uu]; xb[uu] = xc[uu]; }
                int tl = i + 11;
                if (tl > T_STEPS - 1) tl = T_STEPS - 1;
                loadx4(xc, x_r, x_t, xr_base + (size_t)tl * 47, xt_base + (size_t)tl * 2, l);
            }
            if ((i & 7) == 7) LDS_BARRIER();
        }
    } else if (wid == 1) {
        // ===== W1: HA (lag 8) =====
        h2 w[4][24];
#pragma unroll
        for (int g = 0; g < 4; ++g)
#pragma unroll
            for (int u = 0; u < 24; ++u) w[g][u] = h2{(_Float16)0.0f, (_Float16)0.0f};
        if (j < 47) {
#pragma unroll
            for (int g = 0; g < 4; ++g) loadw47h(w[g], &rWhh0[(g * 47 + j) * 47]);
        }
        float c0 = 0.f;
        __syncthreads();
        for (int i = 0; i < TOTAL; ++i) {
            const int s = i - 8;
            float hv = 0.0f;
            if (s >= 0 && s < T_STEPS && j < 47) {
                float4 pa = *(const float4*)&pAring[s & 15][j * 4];
                h2 in[24];
                unpackh(in, &h0f16[(s - 1) & 15][0]);
                float4 pre = dot4h(in, w, pa);
                float iv = sig_f(pre.x), fv = sig_f(pre.y);
                float gv = tanh_f(pre.z), ov = sig_f(pre.w);
                c0 = fmaf(fv, c0, iv * gv);
                hv = ov * tanh_f(c0);
            }
            float hn = dppf<DPP_PAIR>(hv);
            if (s >= 0 && s < T_STEPS && j < 47 && !(j & 1)) {
                h0f16[s & 15][j >> 1] = __builtin_bit_cast(h2, __builtin_amdgcn_cvt_pkrtz(hv, hn));
            }
            if ((i & 7) == 7) LDS_BARRIER();
        }
    } else if (wid == 2) {
        // ===== W2: XB (lag 16) + TT (lag 32) =====
        h2 w[4][24]; float4 bias = {0, 0, 0, 0};
#pragma unroll
        for (int g = 0; g < 4; ++g)
#pragma unroll
            for (int u = 0; u < 24; ++u) w[g][u] = h2{(_Float16)0.0f, (_Float16)0.0f};
        if (j < 47) {
            float bb[4];
#pragma unroll
            for (int g = 0; g < 4; ++g) {
                loadw47h(w[g], &rWih1[(g * 47 + j) * 47]);
                bb[g] = rbih1[g * 47 + j] + rbhh1[g * 47 + j];
            }
            bias = {bb[0], bb[1], bb[2], bb[3]};
        }
        // TT setup
        const int tu  = (l >> 2) & 1;
        const int tg  = l & 3;
        const int thf = (l >> 3) & 1;
        const int R0 = tg * 2 + tu;
        f2 wt[24]; float wx48;
        if (thf == 0) {
            wx48 = 0.f;
#pragma unroll
            for (int k = 0; k < 24; ++k)
                wt[k] = f2{tWih0[R0 * 96 + 2 * k], tWih0[R0 * 96 + 2 * k + 1]};
        } else {
            wx48 = tWih0[R0 * 96 + 48];
#pragma unroll
            for (int k = 0; k < 23; ++k)
                wt[k] = f2{tWih0[R0 * 96 + 49 + 2 * k], tWih0[R0 * 96 + 49 + 2 * k + 1]};
            wt[23] = f2{tWih0[R0 * 96 + 95], 0.f};
        }
        const float bT0 = tbih0[R0] + tbhh0[R0];
        const float wh00 = tWhh0[R0 * 2 + 0], wh01 = tWhh0[R0 * 2 + 1];
        const float wi10 = tWih1[R0 * 2 + 0], wi11 = tWih1[R0 * 2 + 1];
        const float wh10 = tWhh1[R0 * 2 + 0], wh11 = tWhh1[R0 * 2 + 1];
        const float bT1 = tbih1[R0] + tbhh1[R0];
        const bool isg = (tg == 2);
        const float zm = isg ? 2.f : 1.f, sm = isg ? 2.f : 1.f, sa = isg ? -1.f : 0.f;
        float ht00 = 0.f, ht01 = 0.f, ct0u = 0.f;
        float ht10 = 0.f, ht11 = 0.f, ct1u = 0.f;

        __syncthreads();
        for (int i = 0; i < TOTAL; ++i) {
            const int s2 = i - 16;
            if (s2 >= 0 && s2 < T_STEPS && j < 47) {
                h2 in[24];
                unpackh(in, &h0f16[s2 & 15][0]);
                float4 pre = dot4h(in, w, bias);
                *(float4*)&pBring[s2 & 15][j * 4] = pre;
            }
            const int s = i - 32;
            if (s >= 0 && s < T_STEPS) {
                f2 in[24];
                unpack12(in, (const float4*)&tring[s & 63][thf ? 64 : 0]);
                float x48 = tring[s & 63][48];
                f2 av = {0, 0}, bv = {0, 0};
#pragma unroll
                for (int k = 0; k < 12; ++k) {
                    av = __builtin_elementwise_fma(wt[2 * k],     in[2 * k],     av);
                    bv = __builtin_elementwise_fma(wt[2 * k + 1], in[2 * k + 1], bv);
                }
                f2 sv = av + bv;
                float part = fmaf(wx48, x48, sv.x + sv.y);
                float pre0 = part + dppf<DPP_ROR8>(part);
                pre0 += bT0 + wh00 * ht00 + wh01 * ht01;
                float a0 = gate_act(pre0, zm, sm, sa);
                float i0 = dppf<DPP_BCAST0>(a0);
                float f0 = dppf<DPP_BCAST1>(a0);
                float g0 = dppf<DPP_BCAST2>(a0);
                float o0 = dppf<DPP_BCAST3>(a0);
                ct0u = fmaf(f0, ct0u, i0 * g0);
                float htu = o0 * tanh_f(ct0u);
                float hto = dppf<DPP_ROR4>(htu);
                ht00 = (tu == 0) ? htu : hto;
                ht01 = (tu == 0) ? hto : htu;
                float pre1 = bT1 + wi10 * ht00 + wi11 * ht01 + wh10 * ht10 + wh11 * ht11;
                float a1 = gate_act(pre1, zm, sm, sa);
                float ji = dppf<DPP_BCAST0>(a1);
                float jf = dppf<DPP_BCAST1>(a1);
                float jg = dppf<DPP_BCAST2>(a1);
                float jo = dppf<DPP_BCAST3>(a1);
                ct1u = fmaf(jf, ct1u, ji * jg);
                float h1u = jo * tanh_f(ct1u);
                float h1o = dppf<DPP_ROR4>(h1u);
                ht10 = (tu == 0) ? h1u : h1o;
                ht11 = (tu == 0) ? h1o : h1u;
                if (l == 0) {
                    float2 tv = {ht10, ht11};
                    *reinterpret_cast<float2*>(&t_out[((size_t)b * T_STEPS + s) * 2]) = tv;
                }
            }
            if ((i & 7) == 7) LDS_BARRIER();
        }
    } else {
        // ===== W3: HB (lag 24) =====
        h2 w[4][24];
#pragma unroll
        for (int g = 0; g < 4; ++g)
#pragma unroll
            for (int u = 0; u < 24; ++u) w[g][u] = h2{(_Float16)0.0f, (_Float16)0.0f};
        if (j < 47) {
#pragma unroll
            for (int g = 0; g < 4; ++g) loadw47h(w[g], &rWhh1[(g * 47 + j) * 47]);
        }
        float c1 = 0.f;
        __syncthreads();
        for (int i = 0; i < TOTAL; ++i) {
            const int s = i - 24;
            float hv = 0.0f;
            if (s >= 0 && s < T_STEPS && j < 47) {
                float4 pb = *(const float4*)&pBring[s & 15][j * 4];
                h2 in[24];
                unpackh(in, &h1f16[(s - 1) & 15][0]);
                float4 pre = dot4h(in, w, pb);
                float iv = sig_f(pre.x), fv = sig_f(pre.y);
                float gv = tanh_f(pre.z), ov = sig_f(pre.w);
                c1 = fmaf(fv, c1, iv * gv);
                hv = ov * tanh_f(c1);
                tring[s & 63][64 + j] = hv;
                r_out[((size_t)b * T_STEPS + s) * 47 + j] = hv;
            }
            float hn = dppf<DPP_PAIR>(hv);
            if (s >= 0 && s < T_STEPS && j < 47 && !(j & 1)) {
                h1f16[s & 15][j >> 1] = __builtin_bit_cast(h2, __builtin_amdgcn_cvt_pkrtz(hv, hn));
            }
            if ((i & 7) == 7) LDS_BARRIER();
        }
    }
}

extern "C" void kernel_launch(void* const* d_in, const int* in_sizes, int n_in,
                              void* d_out, int out_size, void* d_ws, size_t ws_size,
                              hipStream_t stream) {
    const float* x_r   = (const float*)d_in[0];
    const float* x_t   = (const float*)d_in[1];
    const float* rWih0 = (const float*)d_in[2];
    const float* rWhh0 = (const float*)d_in[3];
    const float* rbih0 = (const float*)d_in[4];
    const float* rbhh0 = (const float*)d_in[5];
    const float* rWih1 = (const float*)d_in[6];
    const float* rWhh1 = (const float*)d_in[7];
    const float* rbih1 = (const float*)d_in[8];
    const float* rbhh1 = (const float*)d_in[9];
    const float* tWih0 = (const float*)d_in[10];
    const float* tWhh0 = (const float*)d_in[11];
    const float* tbih0 = (const float*)d_in[12];
    const float* tbhh0 = (const float*)d_in[13];
    const float* tWih1 = (const float*)d_in[14];
    const float* tWhh1 = (const float*)d_in[15];
    const float* tbih1 = (const float*)d_in[16];
    const float* tbhh1 = (const float*)d_in[17];

    float* r_out = (float*)d_out;
    float* t_out = r_out + (size_t)256 * T_STEPS * 47;

    hipLaunchKernelGGL(adrnn_fused, dim3(256), dim3(256), 0, stream,
                       x_r, x_t, rWih0, rWhh0, rbih0, rbhh0, rWih1, rWhh1, rbih1, rbhh1,
                       tWih0, tWhh0, tbih0, tbhh0, tWih1, tWhh1, tbih1, tbhh1,
                       r_out, t_out);
}

// Round 16
// 1277.095 us; speedup vs baseline: 1.1873x; 1.1367x over previous
//
#include <hip/hip_runtime.h>

#define T_STEPS 2048
#define TOTAL   2064   // T_STEPS + 16 (deepest lag: TT), multiple of 8

typedef float f2 __attribute__((ext_vector_type(2)));
typedef _Float16 h2 __attribute__((ext_vector_type(2)));

__device__ __forceinline__ float fast_rcp(float x) { return __builtin_amdgcn_rcpf(x); }
__device__ __forceinline__ float sig_f(float x) { return fast_rcp(1.0f + __expf(-x)); }
__device__ __forceinline__ float tanh_f(float x) {
    float e = __expf(-2.0f * x);
    return fmaf(2.0f, fast_rcp(1.0f + e), -1.0f);
}
__device__ __forceinline__ float gate_act(float x, float zm, float sm, float sa) {
    float e = __expf(-x * zm);
    return fmaf(fast_rcp(1.0f + e), sm, sa);
}

#if __has_builtin(__builtin_amdgcn_fdot2)
#define FDOT2(a, b, c) __builtin_amdgcn_fdot2((a), (b), (c), false)
#else
__device__ __forceinline__ float FDOT2(h2 a, h2 b, float c) {
    return fmaf((float)a.x, (float)b.x, fmaf((float)a.y, (float)b.y, c));
}
#endif

// Drain ONLY lgkmcnt (LDS) before barrier — never vmcnt (R7 win).
#define LDS_BARRIER() asm volatile("s_waitcnt lgkmcnt(0)\n\ts_barrier" ::: "memory")

#define DPP_BCAST0 0x00
#define DPP_BCAST1 0x55
#define DPP_BCAST2 0xAA
#define DPP_BCAST3 0xFF
#define DPP_PAIR   0xF5
#define DPP_ROR4   0x124
#define DPP_ROR8   0x128
template<int CTRL>
__device__ __forceinline__ float dppf(float x) {
    int r = __builtin_amdgcn_update_dpp(0, __builtin_bit_cast(int, x), CTRL, 0xF, 0xF, true);
    return __builtin_bit_cast(float, r);
}

__device__ __forceinline__ h2 pk16(float a, float b) {
    return __builtin_bit_cast(h2, __builtin_amdgcn_cvt_pkrtz(a, b));
}

// 24 h2 (48 f16) as 6 ds_read_b128
__device__ __forceinline__ void unpackh(h2 (&in)[24], const h2* __restrict__ row) {
    const float4* q = (const float4*)row;
#pragma unroll
    for (int k = 0; k < 6; ++k) {
        float4 v = q[k];
        in[4 * k + 0] = __builtin_bit_cast(h2, v.x);
        in[4 * k + 1] = __builtin_bit_cast(h2, v.y);
        in[4 * k + 2] = __builtin_bit_cast(h2, v.z);
        in[4 * k + 3] = __builtin_bit_cast(h2, v.w);
    }
}
// 28 h2 (56 f16) as 7 ds_read_b128 (x row; only first 25 h2 meaningful)
__device__ __forceinline__ void unpackx(h2 (&in)[28], const h2* __restrict__ row) {
    const float4* q = (const float4*)row;
#pragma unroll
    for (int k = 0; k < 7; ++k) {
        float4 v = q[k];
        in[4 * k + 0] = __builtin_bit_cast(h2, v.x);
        in[4 * k + 1] = __builtin_bit_cast(h2, v.y);
        in[4 * k + 2] = __builtin_bit_cast(h2, v.z);
        in[4 * k + 3] = __builtin_bit_cast(h2, v.w);
    }
}

// 47-col f32 row -> 24 packed f16 pairs (pad last)
__device__ __forceinline__ void loadw47h(h2 (&w)[24], const float* __restrict__ src) {
#pragma unroll
    for (int u = 0; u < 23; ++u)
        w[u] = h2{(_Float16)src[2 * u], (_Float16)src[2 * u + 1]};
    w[23] = h2{(_Float16)src[46], (_Float16)0.0f};
}
// 49-col f32 row -> 25 packed f16 pairs
__device__ __forceinline__ void loadw49h(h2 (&w)[25], const float* __restrict__ src) {
#pragma unroll
    for (int u = 0; u < 24; ++u)
        w[u] = h2{(_Float16)src[2 * u], (_Float16)src[2 * u + 1]};
    w[24] = h2{(_Float16)src[48], (_Float16)0.0f};
}

// staging: lane k holds values {4k..4k+3} of [x_r(47)|x_t(2)] (13 lanes)
__device__ __forceinline__ void loadx4c(float (&dst)[4], const float* __restrict__ x_r,
                                        const float* __restrict__ x_t,
                                        size_t xrb, size_t xtb, int k) {
#pragma unroll
    for (int m = 0; m < 4; ++m) {
        int v = 4 * k + m;
        dst[m] = (v < 47) ? x_r[xrb + v] : ((v < 49) ? x_t[xtb + (v - 47)] : 0.0f);
    }
}

// 3 waves: W0 = full layer-0 (lag 0), W1 = full layer-1 (lag 8), W2 = t-RNN (lag 16) + x staging.
// No pA/pB rings (fused) -> the float4 conflict source is gone; all ring reads are
// wave-broadcast (same address across lanes) -> conflict-free by construction.
__global__ __launch_bounds__(192) void adrnn_fused(
    const float* __restrict__ x_r, const float* __restrict__ x_t,
    const float* __restrict__ rWih0, const float* __restrict__ rWhh0,
    const float* __restrict__ rbih0, const float* __restrict__ rbhh0,
    const float* __restrict__ rWih1, const float* __restrict__ rWhh1,
    const float* __restrict__ rbih1, const float* __restrict__ rbhh1,
    const float* __restrict__ tWih0, const float* __restrict__ tWhh0,
    const float* __restrict__ tbih0, const float* __restrict__ tbhh0,
    const float* __restrict__ tWih1, const float* __restrict__ tWhh1,
    const float* __restrict__ tbih1, const float* __restrict__ tbhh1,
    float* __restrict__ r_out, float* __restrict__ t_out)
{
    __shared__ __align__(16) h2 xring[32][28];   // x(t) f16, slot t&31, 25 h2 used
    __shared__ __align__(16) h2 h0f16[16][24];   // h0(s) f16, slot s&15
    __shared__ __align__(16) h2 h1f16[16][24];   // h1(s) f16, slot s&15

    const int tid = threadIdx.x;
    const int wid = tid >> 6;
    const int l   = tid & 63;
    const int j   = l;
    const int b = blockIdx.x;
    const size_t xr_base = (size_t)b * T_STEPS * 47;
    const size_t xt_base = (size_t)b * T_STEPS * 2;

    for (int k = tid; k < 16 * 24; k += 192) {
        h0f16[k / 24][k % 24] = h2{(_Float16)0.0f, (_Float16)0.0f};
        h1f16[k / 24][k % 24] = h2{(_Float16)0.0f, (_Float16)0.0f};
    }

    if (wid == 0) {
        // ===== W0: layer-0, h0(i) = cell(Wih0*x(i) + Whh0*h0(i-1) + b) =====
        h2 wx[4][25]; h2 wh[4][24]; float bias[4] = {0, 0, 0, 0};
#pragma unroll
        for (int g = 0; g < 4; ++g) {
#pragma unroll
            for (int u = 0; u < 25; ++u) wx[g][u] = h2{(_Float16)0.0f, (_Float16)0.0f};
#pragma unroll
            for (int u = 0; u < 24; ++u) wh[g][u] = h2{(_Float16)0.0f, (_Float16)0.0f};
        }
        if (j < 47) {
#pragma unroll
            for (int g = 0; g < 4; ++g) {
                const int row = g * 47 + j;
                loadw49h(wx[g], &rWih0[row * 49]);
                loadw47h(wh[g], &rWhh0[row * 47]);
                bias[g] = rbih0[row] + rbhh0[row];
            }
        }
        float c0 = 0.f;
        __syncthreads();
        for (int i = 0; i < TOTAL; ++i) {
            float hv = 0.0f;
            if (i < T_STEPS && j < 47) {
                h2 xin[28];
                unpackx(xin, &xring[i & 31][0]);
                h2 hin[24];
                unpackh(hin, &h0f16[(i - 1) & 15][0]);
                float a0 = bias[0], a1 = bias[1], a2 = bias[2], a3 = bias[3];
#pragma unroll
                for (int u = 0; u < 25; ++u) {
                    a0 = FDOT2(wx[0][u], xin[u], a0);
                    a1 = FDOT2(wx[1][u], xin[u], a1);
                    a2 = FDOT2(wx[2][u], xin[u], a2);
                    a3 = FDOT2(wx[3][u], xin[u], a3);
                }
#pragma unroll
                for (int u = 0; u < 24; ++u) {
                    a0 = FDOT2(wh[0][u], hin[u], a0);
                    a1 = FDOT2(wh[1][u], hin[u], a1);
                    a2 = FDOT2(wh[2][u], hin[u], a2);
                    a3 = FDOT2(wh[3][u], hin[u], a3);
                }
                float iv = sig_f(a0), fv = sig_f(a1);
                float gv = tanh_f(a2), ov = sig_f(a3);
                c0 = fmaf(fv, c0, iv * gv);
                hv = ov * tanh_f(c0);
            }
            float hn = dppf<DPP_PAIR>(hv);
            if (i < T_STEPS && j < 47 && !(j & 1)) h0f16[i & 15][j >> 1] = pk16(hv, hn);
            if ((i & 7) == 7) LDS_BARRIER();
        }
    } else if (wid == 1) {
        // ===== W1: layer-1 (lag 8), h1(s) = cell(Wih1*h0(s) + Whh1*h1(s-1) + b) =====
        h2 wx[4][24]; h2 wh[4][24]; float bias[4] = {0, 0, 0, 0};
#pragma unroll
        for (int g = 0; g < 4; ++g) {
#pragma unroll
            for (int u = 0; u < 24; ++u) {
                wx[g][u] = h2{(_Float16)0.0f, (_Float16)0.0f};
                wh[g][u] = h2{(_Float16)0.0f, (_Float16)0.0f};
            }
        }
        if (j < 47) {
#pragma unroll
            for (int g = 0; g < 4; ++g) {
                const int row = g * 47 + j;
                loadw47h(wx[g], &rWih1[row * 47]);
                loadw47h(wh[g], &rWhh1[row * 47]);
                bias[g] = rbih1[row] + rbhh1[row];
            }
        }
        float c1 = 0.f;
        __syncthreads();
        for (int i = 0; i < TOTAL; ++i) {
            const int s = i - 8;
            float hv = 0.0f;
            if (s >= 0 && s < T_STEPS && j < 47) {
                h2 xin[24];
                unpackh(xin, &h0f16[s & 15][0]);
                h2 hin[24];
                unpackh(hin, &h1f16[(s - 1) & 15][0]);
                float a0 = bias[0], a1 = bias[1], a2 = bias[2], a3 = bias[3];
#pragma unroll
                for (int u = 0; u < 24; ++u) {
                    a0 = FDOT2(wx[0][u], xin[u], a0);
                    a1 = FDOT2(wx[1][u], xin[u], a1);
                    a2 = FDOT2(wx[2][u], xin[u], a2);
                    a3 = FDOT2(wx[3][u], xin[u], a3);
                }
#pragma unroll
                for (int u = 0; u < 24; ++u) {
                    a0 = FDOT2(wh[0][u], hin[u], a0);
                    a1 = FDOT2(wh[1][u], hin[u], a1);
                    a2 = FDOT2(wh[2][u], hin[u], a2);
                    a3 = FDOT2(wh[3][u], hin[u], a3);
                }
                float iv = sig_f(a0), fv = sig_f(a1);
                float gv = tanh_f(a2), ov = sig_f(a3);
                c1 = fmaf(fv, c1, iv * gv);
                hv = ov * tanh_f(c1);
                r_out[((size_t)b * T_STEPS + s) * 47 + j] = hv;
            }
            float hn = dppf<DPP_PAIR>(hv);
            if (s >= 0 && s < T_STEPS && j < 47 && !(j & 1)) h1f16[s & 15][j >> 1] = pk16(hv, hn);
            if ((i & 7) == 7) LDS_BARRIER();
        }
    } else {
        // ===== W2: t-RNN (lag 16) + x staging (8 ahead, f16) =====
        const int tu  = (l >> 2) & 1;
        const int tg  = l & 3;
        const int thf = (l >> 3) & 1;
        const int R0 = tg * 2 + tu;
        h2 wt[24]; float wx48;
        if (thf == 0) {
            wx48 = 0.f;
#pragma unroll
            for (int u = 0; u < 24; ++u)
                wt[u] = h2{(_Float16)tWih0[R0 * 96 + 2 * u], (_Float16)tWih0[R0 * 96 + 2 * u + 1]};
        } else {
            wx48 = tWih0[R0 * 96 + 48];
#pragma unroll
            for (int u = 0; u < 23; ++u)
                wt[u] = h2{(_Float16)tWih0[R0 * 96 + 49 + 2 * u], (_Float16)tWih0[R0 * 96 + 49 + 2 * u + 1]};
            wt[23] = h2{(_Float16)tWih0[R0 * 96 + 95], (_Float16)0.0f};
        }
        const float bT0 = tbih0[R0] + tbhh0[R0];
        const float wh00 = tWhh0[R0 * 2 + 0], wh01 = tWhh0[R0 * 2 + 1];
        const float wi10 = tWih1[R0 * 2 + 0], wi11 = tWih1[R0 * 2 + 1];
        const float wh10 = tWhh1[R0 * 2 + 0], wh11 = tWhh1[R0 * 2 + 1];
        const float bT1 = tbih1[R0] + tbhh1[R0];
        const bool isg = (tg == 2);
        const float zm = isg ? 2.f : 1.f, sm = isg ? 2.f : 1.f, sa = isg ? -1.f : 0.f;
        float ht00 = 0.f, ht01 = 0.f, ct0u = 0.f;
        float ht10 = 0.f, ht11 = 0.f, ct1u = 0.f;

        // prologue: stage x(0..7) f16; prefetch x(8),x(9),x(10) into regs
        float xa[4] = {0,0,0,0}, xb[4] = {0,0,0,0}, xc[4] = {0,0,0,0};
        if (l < 13) {
            for (int t = 0; t < 8; ++t) {
                float xv[4];
                loadx4c(xv, x_r, x_t, xr_base + (size_t)t * 47, xt_base + (size_t)t * 2, l);
                xring[t][2 * l]     = pk16(xv[0], xv[1]);
                xring[t][2 * l + 1] = pk16(xv[2], xv[3]);
            }
            loadx4c(xa, x_r, x_t, xr_base + (size_t)8 * 47,  xt_base + (size_t)8 * 2,  l);
            loadx4c(xb, x_r, x_t, xr_base + (size_t)9 * 47,  xt_base + (size_t)9 * 2,  l);
            loadx4c(xc, x_r, x_t, xr_base + (size_t)10 * 47, xt_base + (size_t)10 * 2, l);
        }
        __syncthreads();

        for (int i = 0; i < TOTAL; ++i) {
            // staging first: x(i+8) -> xring (consumed by W0 next group)
            if (l < 13) {
                const int tw = i + 8;
                if (tw < T_STEPS) {
                    xring[tw & 31][2 * l]     = pk16(xa[0], xa[1]);
                    xring[tw & 31][2 * l + 1] = pk16(xa[2], xa[3]);
                }
#pragma unroll
                for (int m = 0; m < 4; ++m) { xa[m] = xb[m]; xb[m] = xc[m]; }
                int tl = i + 11;
                if (tl > T_STEPS - 1) tl = T_STEPS - 1;
                loadx4c(xc, x_r, x_t, xr_base + (size_t)tl * 47, xt_base + (size_t)tl * 2, l);
            }
            const int s = i - 16;
            if (s >= 0 && s < T_STEPS) {
                const h2* src = (thf == 0) ? &xring[s & 31][0] : &h1f16[s & 15][0];
                h2 tin[24];
                unpackh(tin, src);
                float x48v = (float)xring[s & 31][24].x;
                float acc = 0.f;
#pragma unroll
                for (int u = 0; u < 24; ++u) acc = FDOT2(wt[u], tin[u], acc);
                float part = (thf == 1) ? fmaf(wx48, x48v, acc) : acc;
                float pre0 = part + dppf<DPP_ROR8>(part);
                pre0 += bT0 + wh00 * ht00 + wh01 * ht01;
                float a0 = gate_act(pre0, zm, sm, sa);
                float i0 = dppf<DPP_BCAST0>(a0);
                float f0 = dppf<DPP_BCAST1>(a0);
                float g0 = dppf<DPP_BCAST2>(a0);
                float o0 = dppf<DPP_BCAST3>(a0);
                ct0u = fmaf(f0, ct0u, i0 * g0);
                float htu = o0 * tanh_f(ct0u);
                float hto = dppf<DPP_ROR4>(htu);
                ht00 = (tu == 0) ? htu : hto;
                ht01 = (tu == 0) ? hto : htu;
                float pre1 = bT1 + wi10 * ht00 + wi11 * ht01 + wh10 * ht10 + wh11 * ht11;
                float a1 = gate_act(pre1, zm, sm, sa);
                float ji = dppf<DPP_BCAST0>(a1);
                float jf = dppf<DPP_BCAST1>(a1);
                float jg = dppf<DPP_BCAST2>(a1);
                float jo = dppf<DPP_BCAST3>(a1);
                ct1u = fmaf(jf, ct1u, ji * jg);
                float h1u = jo * tanh_f(ct1u);
                float h1o = dppf<DPP_ROR4>(h1u);
                ht10 = (tu == 0) ? h1u : h1o;
                ht11 = (tu == 0) ? h1o : h1u;
                if (l == 0) {
                    float2 tv = {ht10, ht11};
                    *reinterpret_cast<float2*>(&t_out[((size_t)b * T_STEPS + s) * 2]) = tv;
                }
            }
            if ((i & 7) == 7) LDS_BARRIER();
        }
    }
}

extern "C" void kernel_launch(void* const* d_in, const int* in_sizes, int n_in,
                              void* d_out, int out_size, void* d_ws, size_t ws_size,
                              hipStream_t stream) {
    const float* x_r   = (const float*)d_in[0];
    const float* x_t   = (const float*)d_in[1];
    const float* rWih0 = (const float*)d_in[2];
    const float* rWhh0 = (const float*)d_in[3];
    const float* rbih0 = (const float*)d_in[4];
    const float* rbhh0 = (const float*)d_in[5];
    const float* rWih1 = (const float*)d_in[6];
    const float* rWhh1 = (const float*)d_in[7];
    const float* rbih1 = (const float*)d_in[8];
    const float* rbhh1 = (const float*)d_in[9];
    const float* tWih0 = (const float*)d_in[10];
    const float* tWhh0 = (const float*)d_in[11];
    const float* tbih0 = (const float*)d_in[12];
    const float* tbhh0 = (const float*)d_in[13];
    const float* tWih1 = (const float*)d_in[14];
    const float* tWhh1 = (const float*)d_in[15];
    const float* tbih1 = (const float*)d_in[16];
    const float* tbhh1 = (const float*)d_in[17];

    float* r_out = (float*)d_out;
    float* t_out = r_out + (size_t)256 * T_STEPS * 47;

    hipLaunchKernelGGL(adrnn_fused, dim3(256), dim3(192), 0, stream,
                       x_r, x_t, rWih0, rWhh0, rbih0, rbhh0, rWih1, rWhh1, rbih1, rbhh1,
                       tWih0, tWhh0, tbih0, tbhh0, tWih1, tWhh1, tbih1, tbhh1,
                       r_out, t_out);
}

// Round 17
// 1270.787 us; speedup vs baseline: 1.1932x; 1.0050x over previous
//
#include <hip/hip_runtime.h>

#define T_STEPS 2048
#define TOTAL   2064   // T_STEPS + 16 (deepest lag: TT), multiple of 8

typedef float f2 __attribute__((ext_vector_type(2)));
typedef _Float16 h2 __attribute__((ext_vector_type(2)));

__device__ __forceinline__ float fast_rcp(float x) { return __builtin_amdgcn_rcpf(x); }
__device__ __forceinline__ float sig_f(float x) { return fast_rcp(1.0f + __expf(-x)); }
__device__ __forceinline__ float tanh_f(float x) {
    float e = __expf(-2.0f * x);
    return fmaf(2.0f, fast_rcp(1.0f + e), -1.0f);
}
__device__ __forceinline__ float gate_act(float x, float zm, float sm, float sa) {
    float e = __expf(-x * zm);
    return fmaf(fast_rcp(1.0f + e), sm, sa);
}

#if __has_builtin(__builtin_amdgcn_fdot2)
#define FDOT2(a, b, c) __builtin_amdgcn_fdot2((a), (b), (c), false)
#else
__device__ __forceinline__ float FDOT2(h2 a, h2 b, float c) {
    return fmaf((float)a.x, (float)b.x, fmaf((float)a.y, (float)b.y, c));
}
#endif

// Drain ONLY lgkmcnt (LDS) before barrier — never vmcnt (R7 win).
#define LDS_BARRIER() asm volatile("s_waitcnt lgkmcnt(0)\n\ts_barrier" ::: "memory")

#define DPP_BCAST0 0x00
#define DPP_BCAST1 0x55
#define DPP_BCAST2 0xAA
#define DPP_BCAST3 0xFF
#define DPP_PAIR   0xF5
#define DPP_ROR4   0x124
#define DPP_ROR8   0x128
template<int CTRL>
__device__ __forceinline__ float dppf(float x) {
    int r = __builtin_amdgcn_update_dpp(0, __builtin_bit_cast(int, x), CTRL, 0xF, 0xF, true);
    return __builtin_bit_cast(float, r);
}

__device__ __forceinline__ h2 pk16(float a, float b) {
    return __builtin_bit_cast(h2, __builtin_amdgcn_cvt_pkrtz(a, b));
}

__device__ __forceinline__ void unpackh(h2 (&in)[24], const h2* __restrict__ row) {
    const float4* q = (const float4*)row;
#pragma unroll
    for (int k = 0; k < 6; ++k) {
        float4 v = q[k];
        in[4 * k + 0] = __builtin_bit_cast(h2, v.x);
        in[4 * k + 1] = __builtin_bit_cast(h2, v.y);
        in[4 * k + 2] = __builtin_bit_cast(h2, v.z);
        in[4 * k + 3] = __builtin_bit_cast(h2, v.w);
    }
}
__device__ __forceinline__ void unpackx(h2 (&in)[28], const h2* __restrict__ row) {
    const float4* q = (const float4*)row;
#pragma unroll
    for (int k = 0; k < 7; ++k) {
        float4 v = q[k];
        in[4 * k + 0] = __builtin_bit_cast(h2, v.x);
        in[4 * k + 1] = __builtin_bit_cast(h2, v.y);
        in[4 * k + 2] = __builtin_bit_cast(h2, v.z);
        in[4 * k + 3] = __builtin_bit_cast(h2, v.w);
    }
}

__device__ __forceinline__ void loadw47h(h2 (&w)[24], const float* __restrict__ src) {
#pragma unroll
    for (int u = 0; u < 23; ++u)
        w[u] = h2{(_Float16)src[2 * u], (_Float16)src[2 * u + 1]};
    w[23] = h2{(_Float16)src[46], (_Float16)0.0f};
}
__device__ __forceinline__ void loadw49h(h2 (&w)[25], const float* __restrict__ src) {
#pragma unroll
    for (int u = 0; u < 24; ++u)
        w[u] = h2{(_Float16)src[2 * u], (_Float16)src[2 * u + 1]};
    w[24] = h2{(_Float16)src[48], (_Float16)0.0f};
}

__device__ __forceinline__ void loadx4c(float (&dst)[4], const float* __restrict__ x_r,
                                        const float* __restrict__ x_t,
                                        size_t xrb, size_t xtb, int k) {
#pragma unroll
    for (int m = 0; m < 4; ++m) {
        int v = 4 * k + m;
        dst[m] = (v < 47) ? x_r[xrb + v] : ((v < 49) ? x_t[xtb + (v - 47)] : 0.0f);
    }
}

// 3 waves: W0 = full layer-0 (lag 0), W1 = full layer-1 (lag 8), W2 = t-RNN (lag 16) + x staging.
// THE round-17 change: group-loop with #pragma unroll 8 inner body, barrier OUTSIDE the
// unrolled region — lets the compiler software-pipeline non-recurrent LDS reads and
// staging loads across the 7 barrier-free steps (previously each iteration was an
// opaque scheduling unit ending in an asm barrier).
__global__ __launch_bounds__(192) void adrnn_fused(
    const float* __restrict__ x_r, const float* __restrict__ x_t,
    const float* __restrict__ rWih0, const float* __restrict__ rWhh0,
    const float* __restrict__ rbih0, const float* __restrict__ rbhh0,
    const float* __restrict__ rWih1, const float* __restrict__ rWhh1,
    const float* __restrict__ rbih1, const float* __restrict__ rbhh1,
    const float* __restrict__ tWih0, const float* __restrict__ tWhh0,
    const float* __restrict__ tbih0, const float* __restrict__ tbhh0,
    const float* __restrict__ tWih1, const float* __restrict__ tWhh1,
    const float* __restrict__ tbih1, const float* __restrict__ tbhh1,
    float* __restrict__ r_out, float* __restrict__ t_out)
{
    __shared__ __align__(16) h2 xring[32][28];
    __shared__ __align__(16) h2 h0f16[16][24];
    __shared__ __align__(16) h2 h1f16[16][24];

    const int tid = threadIdx.x;
    const int wid = tid >> 6;
    const int l   = tid & 63;
    const int j   = l;
    const int b = blockIdx.x;
    const size_t xr_base = (size_t)b * T_STEPS * 47;
    const size_t xt_base = (size_t)b * T_STEPS * 2;

    for (int k = tid; k < 16 * 24; k += 192) {
        h0f16[k / 24][k % 24] = h2{(_Float16)0.0f, (_Float16)0.0f};
        h1f16[k / 24][k % 24] = h2{(_Float16)0.0f, (_Float16)0.0f};
    }

    if (wid == 0) {
        // ===== W0: layer-0 =====
        h2 wx[4][25]; h2 wh[4][24]; float bias[4] = {0, 0, 0, 0};
#pragma unroll
        for (int g = 0; g < 4; ++g) {
#pragma unroll
            for (int u = 0; u < 25; ++u) wx[g][u] = h2{(_Float16)0.0f, (_Float16)0.0f};
#pragma unroll
            for (int u = 0; u < 24; ++u) wh[g][u] = h2{(_Float16)0.0f, (_Float16)0.0f};
        }
        if (j < 47) {
#pragma unroll
            for (int g = 0; g < 4; ++g) {
                const int row = g * 47 + j;
                loadw49h(wx[g], &rWih0[row * 49]);
                loadw47h(wh[g], &rWhh0[row * 47]);
                bias[g] = rbih0[row] + rbhh0[row];
            }
        }
        float c0 = 0.f;
        __syncthreads();
        for (int g0 = 0; g0 < TOTAL; g0 += 8) {
#pragma unroll
            for (int k8 = 0; k8 < 8; ++k8) {
                const int i = g0 + k8;
                float hv = 0.0f;
                if (i < T_STEPS && j < 47) {
                    h2 xin[28];
                    unpackx(xin, &xring[i & 31][0]);
                    h2 hin[24];
                    unpackh(hin, &h0f16[(i - 1) & 15][0]);
                    float a0 = bias[0], a1 = bias[1], a2 = bias[2], a3 = bias[3];
#pragma unroll
                    for (int u = 0; u < 25; ++u) {
                        a0 = FDOT2(wx[0][u], xin[u], a0);
                        a1 = FDOT2(wx[1][u], xin[u], a1);
                        a2 = FDOT2(wx[2][u], xin[u], a2);
                        a3 = FDOT2(wx[3][u], xin[u], a3);
                    }
#pragma unroll
                    for (int u = 0; u < 24; ++u) {
                        a0 = FDOT2(wh[0][u], hin[u], a0);
                        a1 = FDOT2(wh[1][u], hin[u], a1);
                        a2 = FDOT2(wh[2][u], hin[u], a2);
                        a3 = FDOT2(wh[3][u], hin[u], a3);
                    }
                    float iv = sig_f(a0), fv = sig_f(a1);
                    float gv = tanh_f(a2), ov = sig_f(a3);
                    c0 = fmaf(fv, c0, iv * gv);
                    hv = ov * tanh_f(c0);
                }
                float hn = dppf<DPP_PAIR>(hv);
                if (i < T_STEPS && j < 47 && !(j & 1)) h0f16[i & 15][j >> 1] = pk16(hv, hn);
            }
            LDS_BARRIER();
        }
    } else if (wid == 1) {
        // ===== W1: layer-1 (lag 8) =====
        h2 wx[4][24]; h2 wh[4][24]; float bias[4] = {0, 0, 0, 0};
#pragma unroll
        for (int g = 0; g < 4; ++g) {
#pragma unroll
            for (int u = 0; u < 24; ++u) {
                wx[g][u] = h2{(_Float16)0.0f, (_Float16)0.0f};
                wh[g][u] = h2{(_Float16)0.0f, (_Float16)0.0f};
            }
        }
        if (j < 47) {
#pragma unroll
            for (int g = 0; g < 4; ++g) {
                const int row = g * 47 + j;
                loadw47h(wx[g], &rWih1[row * 47]);
                loadw47h(wh[g], &rWhh1[row * 47]);
                bias[g] = rbih1[row] + rbhh1[row];
            }
        }
        float c1 = 0.f;
        __syncthreads();
        for (int g0 = 0; g0 < TOTAL; g0 += 8) {
#pragma unroll
            for (int k8 = 0; k8 < 8; ++k8) {
                const int i = g0 + k8;
                const int s = i - 8;
                float hv = 0.0f;
                if (s >= 0 && s < T_STEPS && j < 47) {
                    h2 xin[24];
                    unpackh(xin, &h0f16[s & 15][0]);
                    h2 hin[24];
                    unpackh(hin, &h1f16[(s - 1) & 15][0]);
                    float a0 = bias[0], a1 = bias[1], a2 = bias[2], a3 = bias[3];
#pragma unroll
                    for (int u = 0; u < 24; ++u) {
                        a0 = FDOT2(wx[0][u], xin[u], a0);
                        a1 = FDOT2(wx[1][u], xin[u], a1);
                        a2 = FDOT2(wx[2][u], xin[u], a2);
                        a3 = FDOT2(wx[3][u], xin[u], a3);
                    }
#pragma unroll
                    for (int u = 0; u < 24; ++u) {
                        a0 = FDOT2(wh[0][u], hin[u], a0);
                        a1 = FDOT2(wh[1][u], hin[u], a1);
                        a2 = FDOT2(wh[2][u], hin[u], a2);
                        a3 = FDOT2(wh[3][u], hin[u], a3);
                    }
                    float iv = sig_f(a0), fv = sig_f(a1);
                    float gv = tanh_f(a2), ov = sig_f(a3);
                    c1 = fmaf(fv, c1, iv * gv);
                    hv = ov * tanh_f(c1);
                    r_out[((size_t)b * T_STEPS + s) * 47 + j] = hv;
                }
                float hn = dppf<DPP_PAIR>(hv);
                if (s >= 0 && s < T_STEPS && j < 47 && !(j & 1)) h1f16[s & 15][j >> 1] = pk16(hv, hn);
            }
            LDS_BARRIER();
        }
    } else {
        // ===== W2: t-RNN (lag 16) + x staging (8 ahead, f16) =====
        const int tu  = (l >> 2) & 1;
        const int tg  = l & 3;
        const int thf = (l >> 3) & 1;
        const int R0 = tg * 2 + tu;
        h2 wt[24]; float wx48;
        if (thf == 0) {
            wx48 = 0.f;
#pragma unroll
            for (int u = 0; u < 24; ++u)
                wt[u] = h2{(_Float16)tWih0[R0 * 96 + 2 * u], (_Float16)tWih0[R0 * 96 + 2 * u + 1]};
        } else {
            wx48 = tWih0[R0 * 96 + 48];
#pragma unroll
            for (int u = 0; u < 23; ++u)
                wt[u] = h2{(_Float16)tWih0[R0 * 96 + 49 + 2 * u], (_Float16)tWih0[R0 * 96 + 49 + 2 * u + 1]};
            wt[23] = h2{(_Float16)tWih0[R0 * 96 + 95], (_Float16)0.0f};
        }
        const float bT0 = tbih0[R0] + tbhh0[R0];
        const float wh00 = tWhh0[R0 * 2 + 0], wh01 = tWhh0[R0 * 2 + 1];
        const float wi10 = tWih1[R0 * 2 + 0], wi11 = tWih1[R0 * 2 + 1];
        const float wh10 = tWhh1[R0 * 2 + 0], wh11 = tWhh1[R0 * 2 + 1];
        const float bT1 = tbih1[R0] + tbhh1[R0];
        const bool isg = (tg == 2);
        const float zm = isg ? 2.f : 1.f, sm = isg ? 2.f : 1.f, sa = isg ? -1.f : 0.f;
        float ht00 = 0.f, ht01 = 0.f, ct0u = 0.f;
        float ht10 = 0.f, ht11 = 0.f, ct1u = 0.f;

        float xa[4] = {0,0,0,0}, xb[4] = {0,0,0,0}, xc[4] = {0,0,0,0};
        if (l < 13) {
            for (int t = 0; t < 8; ++t) {
                float xv[4];
                loadx4c(xv, x_r, x_t, xr_base + (size_t)t * 47, xt_base + (size_t)t * 2, l);
                xring[t][2 * l]     = pk16(xv[0], xv[1]);
                xring[t][2 * l + 1] = pk16(xv[2], xv[3]);
            }
            loadx4c(xa, x_r, x_t, xr_base + (size_t)8 * 47,  xt_base + (size_t)8 * 2,  l);
            loadx4c(xb, x_r, x_t, xr_base + (size_t)9 * 47,  xt_base + (size_t)9 * 2,  l);
            loadx4c(xc, x_r, x_t, xr_base + (size_t)10 * 47, xt_base + (size_t)10 * 2, l);
        }
        __syncthreads();

        for (int g0 = 0; g0 < TOTAL; g0 += 8) {
#pragma unroll
            for (int k8 = 0; k8 < 8; ++k8) {
                const int i = g0 + k8;
                if (l < 13) {
                    const int tw = i + 8;
                    if (tw < T_STEPS) {
                        xring[tw & 31][2 * l]     = pk16(xa[0], xa[1]);
                        xring[tw & 31][2 * l + 1] = pk16(xa[2], xa[3]);
                    }
#pragma unroll
                    for (int m = 0; m < 4; ++m) { xa[m] = xb[m]; xb[m] = xc[m]; }
                    int tl = i + 11;
                    if (tl > T_STEPS - 1) tl = T_STEPS - 1;
                    loadx4c(xc, x_r, x_t, xr_base + (size_t)tl * 47, xt_base + (size_t)tl * 2, l);
                }
                const int s = i - 16;
                if (s >= 0 && s < T_STEPS) {
                    const h2* src = (thf == 0) ? &xring[s & 31][0] : &h1f16[s & 15][0];
                    h2 tin[24];
                    unpackh(tin, src);
                    float x48v = (float)xring[s & 31][24].x;
                    float acc = 0.f;
#pragma unroll
                    for (int u = 0; u < 24; ++u) acc = FDOT2(wt[u], tin[u], acc);
                    float part = (thf == 1) ? fmaf(wx48, x48v, acc) : acc;
                    float pre0 = part + dppf<DPP_ROR8>(part);
                    pre0 += bT0 + wh00 * ht00 + wh01 * ht01;
                    float a0 = gate_act(pre0, zm, sm, sa);
                    float i0 = dppf<DPP_BCAST0>(a0);
                    float f0 = dppf<DPP_BCAST1>(a0);
                    float g0v = dppf<DPP_BCAST2>(a0);
                    float o0 = dppf<DPP_BCAST3>(a0);
                    ct0u = fmaf(f0, ct0u, i0 * g0v);
                    float htu = o0 * tanh_f(ct0u);
                    float hto = dppf<DPP_ROR4>(htu);
                    ht00 = (tu == 0) ? htu : hto;
                    ht01 = (tu == 0) ? hto : htu;
                    float pre1 = bT1 + wi10 * ht00 + wi11 * ht01 + wh10 * ht10 + wh11 * ht11;
                    float a1 = gate_act(pre1, zm, sm, sa);
                    float ji = dppf<DPP_BCAST0>(a1);
                    float jf = dppf<DPP_BCAST1>(a1);
                    float jg = dppf<DPP_BCAST2>(a1);
                    float jo = dppf<DPP_BCAST3>(a1);
                    ct1u = fmaf(jf, ct1u, ji * jg);
                    float h1u = jo * tanh_f(ct1u);
                    float h1o = dppf<DPP_ROR4>(h1u);
                    ht10 = (tu == 0) ? h1u : h1o;
                    ht11 = (tu == 0) ? h1o : h1u;
                    if (l == 0) {
                        float2 tv = {ht10, ht11};
                        *reinterpret_cast<float2*>(&t_out[((size_t)b * T_STEPS + s) * 2]) = tv;
                    }
                }
            }
            LDS_BARRIER();
        }
    }
}

extern "C" void kernel_launch(void* const* d_in, const int* in_sizes, int n_in,
                              void* d_out, int out_size, void* d_ws, size_t ws_size,
                              hipStream_t stream) {
    const float* x_r   = (const float*)d_in[0];
    const float* x_t   = (const float*)d_in[1];
    const float* rWih0 = (const float*)d_in[2];
    const float* rWhh0 = (const float*)d_in[3];
    const float* rbih0 = (const float*)d_in[4];
    const float* rbhh0 = (const float*)d_in[5];
    const float* rWih1 = (const float*)d_in[6];
    const float* rWhh1 = (const float*)d_in[7];
    const float* rbih1 = (const float*)d_in[8];
    const float* rbhh1 = (const float*)d_in[9];
    const float* tWih0 = (const float*)d_in[10];
    const float* tWhh0 = (const float*)d_in[11];
    const float* tbih0 = (const float*)d_in[12];
    const float* tbhh0 = (const float*)d_in[13];
    const float* tWih1 = (const float*)d_in[14];
    const float* tWhh1 = (const float*)d_in[15];
    const float* tbih1 = (const float*)d_in[16];
    const float* tbhh1 = (const float*)d_in[17];

    float* r_out = (float*)d_out;
    float* t_out = r_out + (size_t)256 * T_STEPS * 47;

    hipLaunchKernelGGL(adrnn_fused, dim3(256), dim3(192), 0, stream,
                       x_r, x_t, rWih0, rWhh0, rbih0, rbhh0, rWih1, rWhh1, rbih1, rbhh1,
                       tWih0, tWhh0, tbih0, tbhh0, tWih1, tWhh1, tbih1, tbhh1,
                       r_out, t_out);
}